// Round 2
// baseline (4820.486 us; speedup 1.0000x reference)
//
#include <hip/hip_runtime.h>
#include <math.h>

#define N_  1536
#define M_  768
#define D_  256
#define HEADS_ 8
#define DH_ 32
#define LAYERS_ 6
#define S_  2304
#define SW_ (S_/32)   // 72 mask words per row
#define KC  64

// ---------------- prep kernels ----------------

__global__ __launch_bounds__(256) void k_absr(const float* __restrict__ r, float* __restrict__ nodes) {
    int i = blockIdx.x * 256 + threadIdx.x;
    if (i < N_) nodes[i] = fabsf(r[i]);
}

__global__ __launch_bounds__(256) void k_synd(const float* __restrict__ r, const float* __restrict__ H,
                                              float* __restrict__ nodes) {
    int row = blockIdx.x;
    int tid = threadIdx.x;
    float s = 0.f;
    for (int j = tid; j < N_; j += 256) {
        float b = (r[j] < 0.f) ? 1.f : 0.f;   // bits = 0.5*(1-sign(r))
        s += H[row * N_ + j] * b;
    }
    for (int o = 32; o; o >>= 1) s += __shfl_down(s, o, 64);
    __shared__ float w4[4];
    if ((tid & 63) == 0) w4[tid >> 6] = s;
    __syncthreads();
    if (tid == 0) {
        float t = w4[0] + w4[1] + w4[2] + w4[3];
        nodes[N_ + row] = fmodf(t, 2.0f);
    }
}

__global__ __launch_bounds__(256) void k_maskpack(const float* __restrict__ mask, unsigned* __restrict__ bits) {
    int w = blockIdx.x * 256 + threadIdx.x;
    if (w >= S_ * SW_) return;
    int row = w / SW_, c0 = (w % SW_) * 32;
    unsigned b = 0;
    const float* mrow = mask + (size_t)row * S_ + c0;
    for (int j = 0; j < 32; ++j)
        if (mrow[j] != 0.f) b |= (1u << j);
    bits[w] = b;
}

__global__ __launch_bounds__(256) void k_embed(const float* __restrict__ src, const float* __restrict__ tt,
                                               const int* __restrict__ tptr, const float* __restrict__ nodes,
                                               float* __restrict__ x) {
    int s = blockIdx.x, d = threadIdx.x;
    int t = tptr[0];
    x[s * D_ + d] = src[s * D_ + d] * nodes[s] * tt[t * D_ + d];
}

// ---------------- fp32 tiled GEMM: C[S x NC] = A[S x K] @ B[K x NC] (+bias)(+relu) ----------------
// 64x64 tile per 256-thread block, each thread 4x4, K-step 16.

__global__ __launch_bounds__(256) void k_sgemm(const float* __restrict__ A, const float* __restrict__ B,
                                               float* __restrict__ C, int K, int NC,
                                               const float* __restrict__ bias, int relu) {
    __shared__ float As[16][64];
    __shared__ float Bs[16][64];
    int tid = threadIdx.x;
    int tx = tid & 15, ty = tid >> 4;
    int r0 = blockIdx.y * 64, c0 = blockIdx.x * 64;
    float acc[4][4] = {};
    const float* Ab = A + r0 * K;

    for (int k0 = 0; k0 < K; k0 += 16) {
        int arow = tid >> 2, ak = (tid & 3) * 4;
        float4 a4 = *(const float4*)(Ab + arow * K + k0 + ak);
        As[ak + 0][arow] = a4.x; As[ak + 1][arow] = a4.y;
        As[ak + 2][arow] = a4.z; As[ak + 3][arow] = a4.w;
        int bk = tid >> 4, bc = (tid & 15) * 4;
        *(float4*)&Bs[bk][bc] = *(const float4*)(B + (k0 + bk) * NC + c0 + bc);
        __syncthreads();
#pragma unroll
        for (int kk = 0; kk < 16; ++kk) {
            float4 a = *(float4*)&As[kk][ty * 4];
            float4 b = *(float4*)&Bs[kk][tx * 4];
            acc[0][0] += a.x * b.x; acc[0][1] += a.x * b.y; acc[0][2] += a.x * b.z; acc[0][3] += a.x * b.w;
            acc[1][0] += a.y * b.x; acc[1][1] += a.y * b.y; acc[1][2] += a.y * b.z; acc[1][3] += a.y * b.w;
            acc[2][0] += a.z * b.x; acc[2][1] += a.z * b.y; acc[2][2] += a.z * b.z; acc[2][3] += a.z * b.w;
            acc[3][0] += a.w * b.x; acc[3][1] += a.w * b.y; acc[3][2] += a.w * b.z; acc[3][3] += a.w * b.w;
        }
        __syncthreads();
    }

    float4 bb = make_float4(0.f, 0.f, 0.f, 0.f);
    if (bias) bb = *(const float4*)(bias + c0 + tx * 4);
#pragma unroll
    for (int i = 0; i < 4; ++i) {
        int row = r0 + ty * 4 + i;
        float4 o;
        o.x = acc[i][0] + bb.x; o.y = acc[i][1] + bb.y;
        o.z = acc[i][2] + bb.z; o.w = acc[i][3] + bb.w;
        if (relu) {
            o.x = fmaxf(o.x, 0.f); o.y = fmaxf(o.y, 0.f);
            o.z = fmaxf(o.z, 0.f); o.w = fmaxf(o.w, 0.f);
        }
        *(float4*)(C + row * NC + c0 + tx * 4) = o;
    }
}

// ---------------- flash attention (fp32), block = (head, 32 q-rows) ----------------
// thread: qi = tid>>3 (32 rows), g = tid&7 ; scores for j=g*8..g*8+7 ; output dims d=g*4..g*4+3

__global__ __launch_bounds__(256) void k_attn(const float* __restrict__ q, const float* __restrict__ k,
                                              const float* __restrict__ v, const unsigned* __restrict__ mbits,
                                              float* __restrict__ o) {
    __shared__ float Ks[KC][DH_];
    __shared__ float Vs[KC][DH_];
    __shared__ float Ps[32][KC];
    int h = blockIdx.x, q0 = blockIdx.y * 32;
    int tid = threadIdx.x;
    int qi = tid >> 3, g = tid & 7;

    float4 qr[8];
    const float* qrow = q + (q0 + qi) * D_ + h * DH_;
#pragma unroll
    for (int i = 0; i < 8; ++i) qr[i] = *(const float4*)(qrow + i * 4);

    float m = -INFINITY, l = 0.f;
    float acc[4] = {0.f, 0.f, 0.f, 0.f};
    const float scale = 0.17677669529663687f;  // 1/sqrt(32)

    for (int c0 = 0; c0 < S_; c0 += KC) {
        {
            int row = tid >> 2, cq = (tid & 3) * 8;
            const float* kp = k + (c0 + row) * D_ + h * DH_ + cq;
            const float* vp = v + (c0 + row) * D_ + h * DH_ + cq;
            *(float4*)&Ks[row][cq]     = *(const float4*)kp;
            *(float4*)&Ks[row][cq + 4] = *(const float4*)(kp + 4);
            *(float4*)&Vs[row][cq]     = *(const float4*)vp;
            *(float4*)&Vs[row][cq + 4] = *(const float4*)(vp + 4);
        }
        __syncthreads();

        unsigned word = mbits[(q0 + qi) * SW_ + (c0 >> 5) + (g >> 2)];
        unsigned mb = (word >> ((g & 3) * 8)) & 0xFFu;  // bit jj==1 -> masked

        float s[8];
        float cmax = -INFINITY;
#pragma unroll
        for (int jj = 0; jj < 8; ++jj) {
            int j = g * 8 + jj;
            float d0 = 0.f, d1 = 0.f, d2 = 0.f, d3 = 0.f;
#pragma unroll
            for (int i = 0; i < 8; ++i) {
                float4 kv = *(float4*)&Ks[j][i * 4];
                d0 += qr[i].x * kv.x; d1 += qr[i].y * kv.y;
                d2 += qr[i].z * kv.z; d3 += qr[i].w * kv.w;
            }
            float sv = ((d0 + d1) + (d2 + d3)) * scale;
            bool masked = (mb >> jj) & 1;
            s[jj] = masked ? -INFINITY : sv;
            cmax = fmaxf(cmax, s[jj]);
        }
        for (int d = 1; d < 8; d <<= 1) cmax = fmaxf(cmax, __shfl_xor(cmax, d, 64));

        float mnew = fmaxf(m, cmax);
        float sc = (mnew == -INFINITY) ? 1.f : expf(m - mnew);
        float psum = 0.f;
#pragma unroll
        for (int jj = 0; jj < 8; ++jj) {
            float p = ((mb >> jj) & 1) ? 0.f : expf(s[jj] - mnew);
            psum += p;
            Ps[qi][g * 8 + jj] = p;
        }
        for (int d = 1; d < 8; d <<= 1) psum += __shfl_xor(psum, d, 64);
        l = l * sc + psum;
        m = mnew;
        acc[0] *= sc; acc[1] *= sc; acc[2] *= sc; acc[3] *= sc;
        __syncthreads();

        for (int j = 0; j < KC; j += 4) {
            float4 p4 = *(float4*)&Ps[qi][j];
            float4 v0 = *(float4*)&Vs[j + 0][g * 4];
            float4 v1 = *(float4*)&Vs[j + 1][g * 4];
            float4 v2 = *(float4*)&Vs[j + 2][g * 4];
            float4 v3 = *(float4*)&Vs[j + 3][g * 4];
            acc[0] += p4.x * v0.x + p4.y * v1.x + p4.z * v2.x + p4.w * v3.x;
            acc[1] += p4.x * v0.y + p4.y * v1.y + p4.z * v2.y + p4.w * v3.y;
            acc[2] += p4.x * v0.z + p4.y * v1.z + p4.z * v2.z + p4.w * v3.z;
            acc[3] += p4.x * v0.w + p4.y * v1.w + p4.z * v2.w + p4.w * v3.w;
        }
        __syncthreads();
    }

    float inv = 1.f / l;
    float4 r;
    r.x = acc[0] * inv; r.y = acc[1] * inv; r.z = acc[2] * inv; r.w = acc[3] * inv;
    *(float4*)(o + (q0 + qi) * D_ + h * DH_ + g * 4) = r;
}

// ---------------- residual add + LayerNorm (row = block, 256 threads = D) ----------------

__global__ __launch_bounds__(256) void k_addln(float* __restrict__ x, const float* __restrict__ add,
                                               const float* __restrict__ gg, const float* __restrict__ bb) {
    int row = blockIdx.x, d = threadIdx.x;
    float val = x[row * D_ + d] + add[row * D_ + d];

    __shared__ float w4[4];
    __shared__ float bc[2];

    float ss = val;
    for (int o = 32; o; o >>= 1) ss += __shfl_down(ss, o, 64);
    if ((d & 63) == 0) w4[d >> 6] = ss;
    __syncthreads();
    if (d == 0) bc[0] = (w4[0] + w4[1] + w4[2] + w4[3]) * (1.f / D_);
    __syncthreads();
    float mu = bc[0];
    float c = val - mu;
    float vs = c * c;
    for (int o = 32; o; o >>= 1) vs += __shfl_down(vs, o, 64);
    __syncthreads();               // ensure mean-phase reads of w4 done
    if ((d & 63) == 0) w4[d >> 6] = vs;
    __syncthreads();
    if (d == 0) bc[1] = (w4[0] + w4[1] + w4[2] + w4[3]) * (1.f / D_);
    __syncthreads();
    float var = bc[1];
    float rr = rsqrtf(var + 1e-6f);
    x[row * D_ + d] = c * rr * gg[d] + bb[d];
}

// ---------------- final projection ----------------

__global__ __launch_bounds__(256) void k_final(const float* __restrict__ x, const float* __restrict__ fcw,
                                               const float* __restrict__ fcb, const float* __restrict__ tnw,
                                               const float* __restrict__ tnb, float* __restrict__ out) {
    int row = blockIdx.x, d = threadIdx.x;
    float p = x[row * D_ + d] * fcw[d];
    for (int o = 32; o; o >>= 1) p += __shfl_down(p, o, 64);
    __shared__ float w4[4];
    if ((d & 63) == 0) w4[d >> 6] = p;
    __syncthreads();
    if (d == 0) {
        float s = w4[0] + w4[1] + w4[2] + w4[3];
        out[row] = (s + fcb[0]) * tnw[0] + tnb[0];
    }
}

// ---------------- launch ----------------

extern "C" void kernel_launch(void* const* d_in, const int* in_sizes, int n_in,
                              void* d_out, int out_size, void* d_ws, size_t ws_size,
                              hipStream_t stream) {
    const float* r_t   = (const float*)d_in[0];
    const float* H     = (const float*)d_in[1];
    const float* mask  = (const float*)d_in[2];
    const float* src   = (const float*)d_in[3];
    const float* tt    = (const float*)d_in[4];
    const float* Wq    = (const float*)d_in[5];
    const float* Wk    = (const float*)d_in[6];
    const float* Wv    = (const float*)d_in[7];
    const float* Wo    = (const float*)d_in[8];
    const float* W1    = (const float*)d_in[9];
    const float* b1    = (const float*)d_in[10];
    const float* W2    = (const float*)d_in[11];
    const float* b2    = (const float*)d_in[12];
    const float* ln1g  = (const float*)d_in[13];
    const float* ln1b  = (const float*)d_in[14];
    const float* ln2g  = (const float*)d_in[15];
    const float* ln2b  = (const float*)d_in[16];
    const float* fcw   = (const float*)d_in[17];
    const float* fcb   = (const float*)d_in[18];
    const float* tnw   = (const float*)d_in[19];
    const float* tnb   = (const float*)d_in[20];
    const int*   tptr  = (const int*)d_in[21];
    float* out = (float*)d_out;

    float* ws    = (float*)d_ws;
    float* x     = ws;
    float* qb    = x   + S_ * D_;
    float* kb    = qb  + S_ * D_;
    float* vb    = kb  + S_ * D_;
    float* ao    = vb  + S_ * D_;
    float* tmp   = ao  + S_ * D_;
    float* h1    = tmp + S_ * D_;
    float* nodes = h1  + S_ * 4 * D_;
    unsigned* mbits = (unsigned*)(nodes + S_);

    k_absr<<<(N_ + 255) / 256, 256, 0, stream>>>(r_t, nodes);
    k_synd<<<M_, 256, 0, stream>>>(r_t, H, nodes);
    k_maskpack<<<(S_ * SW_ + 255) / 256, 256, 0, stream>>>(mask, mbits);
    k_embed<<<S_, 256, 0, stream>>>(src, tt, tptr, nodes, x);

    for (int i = 0; i < LAYERS_; ++i) {
        const float* wq = Wq + i * D_ * D_;
        const float* wk = Wk + i * D_ * D_;
        const float* wv = Wv + i * D_ * D_;
        const float* wo = Wo + i * D_ * D_;
        k_sgemm<<<dim3(4, 36), 256, 0, stream>>>(x, wq, qb, D_, D_, nullptr, 0);
        k_sgemm<<<dim3(4, 36), 256, 0, stream>>>(x, wk, kb, D_, D_, nullptr, 0);
        k_sgemm<<<dim3(4, 36), 256, 0, stream>>>(x, wv, vb, D_, D_, nullptr, 0);
        k_attn<<<dim3(HEADS_, S_ / 32), 256, 0, stream>>>(qb, kb, vb, mbits, ao);
        k_sgemm<<<dim3(4, 36), 256, 0, stream>>>(ao, wo, tmp, D_, D_, nullptr, 0);
        k_addln<<<S_, 256, 0, stream>>>(x, tmp, ln1g + i * D_, ln1b + i * D_);
        k_sgemm<<<dim3(16, 36), 256, 0, stream>>>(x, W1 + i * D_ * 4 * D_, h1, D_, 4 * D_, b1 + i * 4 * D_, 1);
        k_sgemm<<<dim3(4, 36), 256, 0, stream>>>(h1, W2 + i * 4 * D_ * D_, tmp, 4 * D_, D_, b2 + i * D_, 0);
        k_addln<<<S_, 256, 0, stream>>>(x, tmp, ln2g + i * D_, ln2b + i * D_);
    }

    k_final<<<N_, 256, 0, stream>>>(x, fcw, fcb, tnw, tnb, out);
}

// Round 4
// 2349.124 us; speedup vs baseline: 2.0520x; 2.0520x over previous
//
#include <hip/hip_runtime.h>
#include <math.h>

#define N_  1536
#define M_  768
#define D_  256
#define HEADS_ 8
#define DH_ 32
#define LAYERS_ 6
#define S_  2304
#define SW_ (S_/32)   // 72 mask words per row
#define KB_ 64        // k-tile
#define QB_ 32        // q-rows per block

// ---------------- prep kernels ----------------

__global__ __launch_bounds__(256) void k_absr(const float* __restrict__ r, float* __restrict__ nodes) {
    int i = blockIdx.x * 256 + threadIdx.x;
    if (i < N_) nodes[i] = fabsf(r[i]);
}

__global__ __launch_bounds__(256) void k_synd(const float* __restrict__ r, const float* __restrict__ H,
                                              float* __restrict__ nodes) {
    int row = blockIdx.x;
    int tid = threadIdx.x;
    float s = 0.f;
    for (int j = tid; j < N_; j += 256) {
        float b = (r[j] < 0.f) ? 1.f : 0.f;
        s += H[row * N_ + j] * b;
    }
    for (int o = 32; o; o >>= 1) s += __shfl_down(s, o, 64);
    __shared__ float w4[4];
    if ((tid & 63) == 0) w4[tid >> 6] = s;
    __syncthreads();
    if (tid == 0) {
        float t = w4[0] + w4[1] + w4[2] + w4[3];
        nodes[N_ + row] = fmodf(t, 2.0f);
    }
}

__global__ __launch_bounds__(256) void k_maskpack(const float* __restrict__ mask, unsigned* __restrict__ bits) {
    int w = blockIdx.x * 256 + threadIdx.x;
    if (w >= S_ * SW_) return;
    int row = w / SW_, c0 = (w % SW_) * 32;
    unsigned b = 0;
    const float* mrow = mask + (size_t)row * S_ + c0;
    for (int j = 0; j < 32; ++j)
        if (mrow[j] != 0.f) b |= (1u << j);
    bits[w] = b;
}

__global__ __launch_bounds__(256) void k_embed(const float* __restrict__ src, const float* __restrict__ tt,
                                               const int* __restrict__ tptr, const float* __restrict__ nodes,
                                               float* __restrict__ x) {
    int s = blockIdx.x, d = threadIdx.x;
    int t = tptr[0];
    x[s * D_ + d] = src[s * D_ + d] * nodes[s] * tt[t * D_ + d];
}

// ---------------- fp32 tiled GEMM ----------------

__global__ __launch_bounds__(256) void k_sgemm(const float* __restrict__ A, const float* __restrict__ B,
                                               float* __restrict__ C, int K, int NC,
                                               const float* __restrict__ bias, int relu) {
    __shared__ float As[16][64];
    __shared__ float Bs[16][64];
    int tid = threadIdx.x;
    int tx = tid & 15, ty = tid >> 4;
    int r0 = blockIdx.y * 64, c0 = blockIdx.x * 64;
    float acc[4][4] = {};
    const float* Ab = A + r0 * K;

    for (int k0 = 0; k0 < K; k0 += 16) {
        int arow = tid >> 2, ak = (tid & 3) * 4;
        float4 a4 = *(const float4*)(Ab + arow * K + k0 + ak);
        As[ak + 0][arow] = a4.x; As[ak + 1][arow] = a4.y;
        As[ak + 2][arow] = a4.z; As[ak + 3][arow] = a4.w;
        int bk = tid >> 4, bc = (tid & 15) * 4;
        *(float4*)&Bs[bk][bc] = *(const float4*)(B + (k0 + bk) * NC + c0 + bc);
        __syncthreads();
#pragma unroll
        for (int kk = 0; kk < 16; ++kk) {
            float4 a = *(float4*)&As[kk][ty * 4];
            float4 b = *(float4*)&Bs[kk][tx * 4];
            acc[0][0] += a.x * b.x; acc[0][1] += a.x * b.y; acc[0][2] += a.x * b.z; acc[0][3] += a.x * b.w;
            acc[1][0] += a.y * b.x; acc[1][1] += a.y * b.y; acc[1][2] += a.y * b.z; acc[1][3] += a.y * b.w;
            acc[2][0] += a.z * b.x; acc[2][1] += a.z * b.y; acc[2][2] += a.z * b.z; acc[2][3] += a.z * b.w;
            acc[3][0] += a.w * b.x; acc[3][1] += a.w * b.y; acc[3][2] += a.w * b.z; acc[3][3] += a.w * b.w;
        }
        __syncthreads();
    }

    float4 bb = make_float4(0.f, 0.f, 0.f, 0.f);
    if (bias) bb = *(const float4*)(bias + c0 + tx * 4);
#pragma unroll
    for (int i = 0; i < 4; ++i) {
        int row = r0 + ty * 4 + i;
        float4 o;
        o.x = acc[i][0] + bb.x; o.y = acc[i][1] + bb.y;
        o.z = acc[i][2] + bb.z; o.w = acc[i][3] + bb.w;
        if (relu) {
            o.x = fmaxf(o.x, 0.f); o.y = fmaxf(o.y, 0.f);
            o.z = fmaxf(o.z, 0.f); o.w = fmaxf(o.w, 0.f);
        }
        *(float4*)(C + row * NC + c0 + tx * 4) = o;
    }
}

// ---------------- flash attention v2: GEMM-shaped, conflict-free LDS ----------------
// Block = (head h, 32 q-rows). 256 threads: tx = tid&15 (k-quads / dh-pairs), ty = tid>>4 (q-pairs).
// Score tile 32q x 64k: thread computes 2q x 4k. PV: thread computes 2q x 2dh.
// Bank math (32 banks x 4B):
//   Qt[32][32]  reads float2 @ col ty*2        -> 4 addrs, rest broadcast: free
//   Kt[32][64]  reads float4 @ col tx*4        -> 16 addrs over 256B: 2-way (free)
//   P [32][68]  reads scalar, rows 4-bank apart-> distinct banks: free
//   Vs[64][36]  reads float2 @ col tx*2        -> 32 banks exactly once: free

__global__ __launch_bounds__(256) void k_attn(const float* __restrict__ q, const float* __restrict__ k,
                                              const float* __restrict__ v, const unsigned* __restrict__ mbits,
                                              float* __restrict__ o) {
    __shared__ float Qt[DH_][QB_];       // 4 KB  (dh-major)
    __shared__ float Kt[DH_][KB_];       // 8 KB  (dh-major)
    __shared__ float Vs[KB_][36];        // 9 KB  (row-major, padded 32->36)
    __shared__ float P [QB_][68];        // 8.5 KB (padded 64->68)

    int h = blockIdx.x, q0 = blockIdx.y * QB_;
    int tid = threadIdx.x;
    int tx = tid & 15, ty = tid >> 4;
    int row0 = ty * 2;

    // stage Q^T once: r = tid&31 (q-row), dh0 = (tid>>5)*4
    {
        int r = tid & 31, dh0 = (tid >> 5) * 4;
        float4 qv = *(const float4*)(q + (size_t)(q0 + r) * D_ + h * DH_ + dh0);
        Qt[dh0 + 0][r] = qv.x; Qt[dh0 + 1][r] = qv.y;
        Qt[dh0 + 2][r] = qv.z; Qt[dh0 + 3][r] = qv.w;
    }

    float m0 = -INFINITY, m1 = -INFINITY, l0 = 0.f, l1 = 0.f;
    float acc00 = 0.f, acc01 = 0.f, acc10 = 0.f, acc11 = 0.f;
    const float scale = 0.17677669529663687f;  // 1/sqrt(32)

    for (int c0 = 0; c0 < S_; c0 += KB_) {
        __syncthreads();   // prev PV reads done before overwriting tiles
        {
            // K: kr = tid&63, gk = (tid>>6)*8 ; transposed scalar writes (2-way: free)
            int kr = tid & 63, gk = (tid >> 6) * 8;
            const float* kp = k + (size_t)(c0 + kr) * D_ + h * DH_ + gk;
            float4 ka = *(const float4*)kp;
            float4 kc = *(const float4*)(kp + 4);
            Kt[gk + 0][kr] = ka.x; Kt[gk + 1][kr] = ka.y;
            Kt[gk + 2][kr] = ka.z; Kt[gk + 3][kr] = ka.w;
            Kt[gk + 4][kr] = kc.x; Kt[gk + 5][kr] = kc.y;
            Kt[gk + 6][kr] = kc.z; Kt[gk + 7][kr] = kc.w;
            // V: kr2 = tid>>2, g4 = (tid&3)*8 ; row-major float4 writes into padded rows
            int kr2 = tid >> 2, g4 = (tid & 3) * 8;
            const float* vp = v + (size_t)(c0 + kr2) * D_ + h * DH_ + g4;
            float4 va = *(const float4*)vp;
            float4 vb = *(const float4*)(vp + 4);
            *(float4*)&Vs[kr2][g4]     = va;
            *(float4*)&Vs[kr2][g4 + 4] = vb;
        }
        __syncthreads();

        // ---- scores: 2q x 4k per thread over dh=32 ----
        float s00 = 0.f, s01 = 0.f, s02 = 0.f, s03 = 0.f;
        float s10 = 0.f, s11 = 0.f, s12 = 0.f, s13 = 0.f;
#pragma unroll 8
        for (int dh = 0; dh < DH_; ++dh) {
            float2 qa = *(float2*)&Qt[dh][row0];
            float4 kb = *(float4*)&Kt[dh][tx * 4];
            s00 += qa.x * kb.x; s01 += qa.x * kb.y; s02 += qa.x * kb.z; s03 += qa.x * kb.w;
            s10 += qa.y * kb.x; s11 += qa.y * kb.y; s12 += qa.y * kb.z; s13 += qa.y * kb.w;
        }

        unsigned w0 = mbits[(size_t)(q0 + row0 + 0) * SW_ + (c0 >> 5) + (tx >> 3)];
        unsigned w1 = mbits[(size_t)(q0 + row0 + 1) * SW_ + (c0 >> 5) + (tx >> 3)];
        unsigned mb0 = (w0 >> ((tx & 7) * 4)) & 0xFu;
        unsigned mb1 = (w1 >> ((tx & 7) * 4)) & 0xFu;

        s00 = (mb0 & 1u) ? -INFINITY : s00 * scale;
        s01 = (mb0 & 2u) ? -INFINITY : s01 * scale;
        s02 = (mb0 & 4u) ? -INFINITY : s02 * scale;
        s03 = (mb0 & 8u) ? -INFINITY : s03 * scale;
        s10 = (mb1 & 1u) ? -INFINITY : s10 * scale;
        s11 = (mb1 & 2u) ? -INFINITY : s11 * scale;
        s12 = (mb1 & 4u) ? -INFINITY : s12 * scale;
        s13 = (mb1 & 8u) ? -INFINITY : s13 * scale;

        float rm0 = fmaxf(fmaxf(s00, s01), fmaxf(s02, s03));
        float rm1 = fmaxf(fmaxf(s10, s11), fmaxf(s12, s13));
#pragma unroll
        for (int d = 1; d < 16; d <<= 1) {
            rm0 = fmaxf(rm0, __shfl_xor(rm0, d, 16));
            rm1 = fmaxf(rm1, __shfl_xor(rm1, d, 16));
        }

        float mn0 = fmaxf(m0, rm0), mn1 = fmaxf(m1, rm1);
        float sc0 = (mn0 == -INFINITY) ? 1.f : __expf(m0 - mn0);
        float sc1 = (mn1 == -INFINITY) ? 1.f : __expf(m1 - mn1);

        float p00 = (mb0 & 1u) ? 0.f : __expf(s00 - mn0);
        float p01 = (mb0 & 2u) ? 0.f : __expf(s01 - mn0);
        float p02 = (mb0 & 4u) ? 0.f : __expf(s02 - mn0);
        float p03 = (mb0 & 8u) ? 0.f : __expf(s03 - mn0);
        float p10 = (mb1 & 1u) ? 0.f : __expf(s10 - mn1);
        float p11 = (mb1 & 2u) ? 0.f : __expf(s11 - mn1);
        float p12 = (mb1 & 4u) ? 0.f : __expf(s12 - mn1);
        float p13 = (mb1 & 8u) ? 0.f : __expf(s13 - mn1);

        float ps0 = p00 + p01 + p02 + p03;
        float ps1 = p10 + p11 + p12 + p13;
#pragma unroll
        for (int d = 1; d < 16; d <<= 1) {
            ps0 += __shfl_xor(ps0, d, 16);
            ps1 += __shfl_xor(ps1, d, 16);
        }
        l0 = l0 * sc0 + ps0;  m0 = mn0;
        l1 = l1 * sc1 + ps1;  m1 = mn1;
        acc00 *= sc0; acc01 *= sc0;
        acc10 *= sc1; acc11 *= sc1;

        *(float4*)&P[row0 + 0][tx * 4] = make_float4(p00, p01, p02, p03);
        *(float4*)&P[row0 + 1][tx * 4] = make_float4(p10, p11, p12, p13);
        __syncthreads();

        // ---- PV: 2q x 2dh per thread over 64 keys ----
#pragma unroll 8
        for (int j = 0; j < KB_; ++j) {
            float pa = P[row0 + 0][j];
            float pb = P[row0 + 1][j];
            float2 vv = *(float2*)&Vs[j][tx * 2];
            acc00 += pa * vv.x; acc01 += pa * vv.y;
            acc10 += pb * vv.x; acc11 += pb * vv.y;
        }
    }

    float inv0 = 1.f / l0, inv1 = 1.f / l1;
    *(float2*)(o + (size_t)(q0 + row0 + 0) * D_ + h * DH_ + tx * 2) = make_float2(acc00 * inv0, acc01 * inv0);
    *(float2*)(o + (size_t)(q0 + row0 + 1) * D_ + h * DH_ + tx * 2) = make_float2(acc10 * inv1, acc11 * inv1);
}

// ---------------- residual add + LayerNorm ----------------

__global__ __launch_bounds__(256) void k_addln(float* __restrict__ x, const float* __restrict__ add,
                                               const float* __restrict__ gg, const float* __restrict__ bb) {
    int row = blockIdx.x, d = threadIdx.x;
    float val = x[row * D_ + d] + add[row * D_ + d];

    __shared__ float w4[4];
    __shared__ float bc[2];

    float ss = val;
    for (int o = 32; o; o >>= 1) ss += __shfl_down(ss, o, 64);
    if ((d & 63) == 0) w4[d >> 6] = ss;
    __syncthreads();
    if (d == 0) bc[0] = (w4[0] + w4[1] + w4[2] + w4[3]) * (1.f / D_);
    __syncthreads();
    float mu = bc[0];
    float c = val - mu;
    float vs = c * c;
    for (int o = 32; o; o >>= 1) vs += __shfl_down(vs, o, 64);
    __syncthreads();
    if ((d & 63) == 0) w4[d >> 6] = vs;
    __syncthreads();
    if (d == 0) bc[1] = (w4[0] + w4[1] + w4[2] + w4[3]) * (1.f / D_);
    __syncthreads();
    float var = bc[1];
    float rr = rsqrtf(var + 1e-6f);
    x[row * D_ + d] = c * rr * gg[d] + bb[d];
}

// ---------------- final projection ----------------

__global__ __launch_bounds__(256) void k_final(const float* __restrict__ x, const float* __restrict__ fcw,
                                               const float* __restrict__ fcb, const float* __restrict__ tnw,
                                               const float* __restrict__ tnb, float* __restrict__ out) {
    int row = blockIdx.x, d = threadIdx.x;
    float p = x[row * D_ + d] * fcw[d];
    for (int o = 32; o; o >>= 1) p += __shfl_down(p, o, 64);
    __shared__ float w4[4];
    if ((d & 63) == 0) w4[d >> 6] = p;
    __syncthreads();
    if (d == 0) {
        float s = w4[0] + w4[1] + w4[2] + w4[3];
        out[row] = (s + fcb[0]) * tnw[0] + tnb[0];
    }
}

// ---------------- launch ----------------

extern "C" void kernel_launch(void* const* d_in, const int* in_sizes, int n_in,
                              void* d_out, int out_size, void* d_ws, size_t ws_size,
                              hipStream_t stream) {
    const float* r_t   = (const float*)d_in[0];
    const float* H     = (const float*)d_in[1];
    const float* mask  = (const float*)d_in[2];
    const float* src   = (const float*)d_in[3];
    const float* tt    = (const float*)d_in[4];
    const float* Wq    = (const float*)d_in[5];
    const float* Wk    = (const float*)d_in[6];
    const float* Wv    = (const float*)d_in[7];
    const float* Wo    = (const float*)d_in[8];
    const float* W1    = (const float*)d_in[9];
    const float* b1    = (const float*)d_in[10];
    const float* W2    = (const float*)d_in[11];
    const float* b2    = (const float*)d_in[12];
    const float* ln1g  = (const float*)d_in[13];
    const float* ln1b  = (const float*)d_in[14];
    const float* ln2g  = (const float*)d_in[15];
    const float* ln2b  = (const float*)d_in[16];
    const float* fcw   = (const float*)d_in[17];
    const float* fcb   = (const float*)d_in[18];
    const float* tnw   = (const float*)d_in[19];
    const float* tnb   = (const float*)d_in[20];
    const int*   tptr  = (const int*)d_in[21];
    float* out = (float*)d_out;

    float* ws    = (float*)d_ws;
    float* x     = ws;
    float* qb    = x   + S_ * D_;
    float* kb    = qb  + S_ * D_;
    float* vb    = kb  + S_ * D_;
    float* ao    = vb  + S_ * D_;
    float* tmp   = ao  + S_ * D_;
    float* h1    = tmp + S_ * D_;
    float* nodes = h1  + S_ * 4 * D_;
    unsigned* mbits = (unsigned*)(nodes + S_);

    k_absr<<<(N_ + 255) / 256, 256, 0, stream>>>(r_t, nodes);
    k_synd<<<M_, 256, 0, stream>>>(r_t, H, nodes);
    k_maskpack<<<(S_ * SW_ + 255) / 256, 256, 0, stream>>>(mask, mbits);
    k_embed<<<S_, 256, 0, stream>>>(src, tt, tptr, nodes, x);

    for (int i = 0; i < LAYERS_; ++i) {
        const float* wq = Wq + i * D_ * D_;
        const float* wk = Wk + i * D_ * D_;
        const float* wv = Wv + i * D_ * D_;
        const float* wo = Wo + i * D_ * D_;
        k_sgemm<<<dim3(4, 36), 256, 0, stream>>>(x, wq, qb, D_, D_, nullptr, 0);
        k_sgemm<<<dim3(4, 36), 256, 0, stream>>>(x, wk, kb, D_, D_, nullptr, 0);
        k_sgemm<<<dim3(4, 36), 256, 0, stream>>>(x, wv, vb, D_, D_, nullptr, 0);
        k_attn<<<dim3(HEADS_, S_ / QB_), 256, 0, stream>>>(qb, kb, vb, mbits, ao);
        k_sgemm<<<dim3(4, 36), 256, 0, stream>>>(ao, wo, tmp, D_, D_, nullptr, 0);
        k_addln<<<S_, 256, 0, stream>>>(x, tmp, ln1g + i * D_, ln1b + i * D_);
        k_sgemm<<<dim3(16, 36), 256, 0, stream>>>(x, W1 + i * D_ * 4 * D_, h1, D_, 4 * D_, b1 + i * 4 * D_, 1);
        k_sgemm<<<dim3(4, 36), 256, 0, stream>>>(h1, W2 + i * 4 * D_ * D_, tmp, 4 * D_, D_, b2 + i * D_, 0);
        k_addln<<<S_, 256, 0, stream>>>(x, tmp, ln2g + i * D_, ln2b + i * D_);
    }

    k_final<<<N_, 256, 0, stream>>>(x, fcw, fcb, tnw, tnb, out);
}

// Round 6
// 1494.244 us; speedup vs baseline: 3.2260x; 1.5721x over previous
//
#include <hip/hip_runtime.h>
#include <math.h>

#define N_  1536
#define M_  768
#define D_  256
#define HEADS_ 8
#define DH_ 32
#define LAYERS_ 6
#define S_  2304
#define SW_ (S_/32)   // 72 mask words per row

typedef __attribute__((ext_vector_type(8))) short  s16x8;
typedef __attribute__((ext_vector_type(8))) __bf16 bf16x8;
typedef __attribute__((ext_vector_type(4))) float  f32x4;

static __device__ __forceinline__ f32x4 mfma16(s16x8 a, s16x8 b, f32x4 c) {
    return __builtin_amdgcn_mfma_f32_16x16x32_bf16(
        __builtin_bit_cast(bf16x8, a), __builtin_bit_cast(bf16x8, b), c, 0, 0, 0);
}

static __device__ __forceinline__ short f2bf(float f) {
    unsigned u = __builtin_bit_cast(unsigned, f);
    unsigned r = u + 0x7FFFu + ((u >> 16) & 1u);   // RNE to bf16
    return (short)(r >> 16);
}
static __device__ __forceinline__ float bf2f(short s) {
    unsigned u = ((unsigned)(unsigned short)s) << 16;
    return __builtin_bit_cast(float, u);
}
static __device__ __forceinline__ void splitf(float f, short& h, short& l) {
    h = f2bf(f);
    l = f2bf(f - bf2f(h));
}

// ---------------- prep kernels ----------------

__global__ __launch_bounds__(256) void k_absr(const float* __restrict__ r, float* __restrict__ nodes) {
    int i = blockIdx.x * 256 + threadIdx.x;
    if (i < N_) nodes[i] = fabsf(r[i]);
}

__global__ __launch_bounds__(256) void k_synd(const float* __restrict__ r, const float* __restrict__ H,
                                              float* __restrict__ nodes) {
    int row = blockIdx.x;
    int tid = threadIdx.x;
    float s = 0.f;
    for (int j = tid; j < N_; j += 256) {
        float b = (r[j] < 0.f) ? 1.f : 0.f;
        s += H[row * N_ + j] * b;
    }
    for (int o = 32; o; o >>= 1) s += __shfl_down(s, o, 64);
    __shared__ float w4[4];
    if ((tid & 63) == 0) w4[tid >> 6] = s;
    __syncthreads();
    if (tid == 0) {
        float t = w4[0] + w4[1] + w4[2] + w4[3];
        nodes[N_ + row] = fmodf(t, 2.0f);
    }
}

__global__ __launch_bounds__(256) void k_maskpack(const float* __restrict__ mask, unsigned* __restrict__ bits) {
    int w = blockIdx.x * 256 + threadIdx.x;
    if (w >= S_ * SW_) return;
    int row = w / SW_, c0 = (w % SW_) * 32;
    unsigned b = 0;
    const float* mrow = mask + (size_t)row * S_ + c0;
    for (int j = 0; j < 32; ++j)
        if (mrow[j] != 0.f) b |= (1u << j);
    bits[w] = b;
}

__global__ __launch_bounds__(256) void k_embed(const float* __restrict__ src, const float* __restrict__ tt,
                                               const int* __restrict__ tptr, const float* __restrict__ nodes,
                                               float* __restrict__ x) {
    int s = blockIdx.x, d = threadIdx.x;
    int t = tptr[0];
    x[s * D_ + d] = src[s * D_ + d] * nodes[s] * tt[t * D_ + d];
}

// ---------------- weight transpose + bf16 hi/lo split ----------------
// W[K][NC] fp32 -> WT_hi/lo[NC][K] bf16.  grid (NC/32, K/32, LAYERS)

__global__ __launch_bounds__(256) void k_wsplit(const float* __restrict__ W, short* __restrict__ oh,
                                                short* __restrict__ ol, int K, int NC,
                                                long in_ls, long out_ls) {
    __shared__ float T[32][33];
    int z = blockIdx.z;
    const float* Wz = W + (size_t)z * in_ls;
    short* ohz = oh + (size_t)z * out_ls;
    short* olz = ol + (size_t)z * out_ls;
    int n0 = blockIdx.x * 32, k0 = blockIdx.y * 32;
    int t = threadIdx.x;
    int r = t >> 3, c4 = (t & 7) * 4;
    float4 v = *(const float4*)(Wz + (size_t)(k0 + r) * NC + n0 + c4);
    T[r][c4 + 0] = v.x; T[r][c4 + 1] = v.y; T[r][c4 + 2] = v.z; T[r][c4 + 3] = v.w;
    __syncthreads();
    int n = t >> 3, k4 = (t & 7) * 4;
#pragma unroll
    for (int i = 0; i < 4; ++i) {
        float f = T[k4 + i][n];
        short hh, ll; splitf(f, hh, ll);
        ohz[(size_t)(n0 + n) * K + k0 + k4 + i] = hh;
        olz[(size_t)(n0 + n) * K + k0 + k4 + i] = ll;
    }
}

// ---------------- MFMA GEMM: C[M x NC] = A[M x K] @ B[K x NC] ----------------
// A fp32 row-major (split to bf16 hi/lo during staging); B pre-split as BT[NC][K] bf16 hi/lo.
// Block: 256 thr = 4 waves. Tile 32(M) x 64(N). Wave w: n-half = w&1, K-half = w>>1 (wave-split-K).
// 3-product per tile: Ah*Bh + Al*Bh + Ah*Bl. LDS rows padded to 72 shorts (144B) -> <=2-way banks.

__global__ __launch_bounds__(256) void k_mgemm(const float* __restrict__ A, const short* __restrict__ BTh,
                                               const short* __restrict__ BTl, float* __restrict__ C,
                                               int K, int NC, const float* __restrict__ bias, int relu) {
    __shared__ short Ah[32][72], Al[32][72];
    __shared__ short Bh[64][72], Bl[64][72];
    int tid = threadIdx.x;
    int w = tid >> 6, lane = tid & 63;
    int n0w = (w & 1) * 32, kh = w >> 1;
    int r0 = blockIdx.y * 32, c0 = blockIdx.x * 64;
    int g = lane >> 4, cl = lane & 15;

    f32x4 acc[2][2];
#pragma unroll
    for (int mt = 0; mt < 2; ++mt)
#pragma unroll
        for (int nt = 0; nt < 2; ++nt) acc[mt][nt] = (f32x4){0.f, 0.f, 0.f, 0.f};

    int arow = tid >> 3, akq = (tid & 7) * 8;
    int bn = tid >> 2, bkq = (tid & 3) * 16;

    for (int k0 = 0; k0 < K; k0 += 64) {
        __syncthreads();
        {   // stage A (fp32 -> hi/lo)
            const float* ap = A + (size_t)(r0 + arow) * K + k0 + akq;
            float4 a0 = *(const float4*)ap, a1 = *(const float4*)(ap + 4);
            float av[8] = {a0.x, a0.y, a0.z, a0.w, a1.x, a1.y, a1.z, a1.w};
            s16x8 vh, vl;
#pragma unroll
            for (int i = 0; i < 8; ++i) { short hh, ll; splitf(av[i], hh, ll); vh[i] = hh; vl[i] = ll; }
            *(s16x8*)&Ah[arow][akq] = vh;
            *(s16x8*)&Al[arow][akq] = vl;
        }
        {   // stage B (bf16 direct)
            const short* bph = BTh + (size_t)(c0 + bn) * K + k0 + bkq;
            const short* bpl = BTl + (size_t)(c0 + bn) * K + k0 + bkq;
            *(s16x8*)&Bh[bn][bkq]     = *(const s16x8*)bph;
            *(s16x8*)&Bh[bn][bkq + 8] = *(const s16x8*)(bph + 8);
            *(s16x8*)&Bl[bn][bkq]     = *(const s16x8*)bpl;
            *(s16x8*)&Bl[bn][bkq + 8] = *(const s16x8*)(bpl + 8);
        }
        __syncthreads();
        int kb = kh * 32 + g * 8;
        s16x8 fAh0 = *(s16x8*)&Ah[cl][kb],      fAl0 = *(s16x8*)&Al[cl][kb];
        s16x8 fAh1 = *(s16x8*)&Ah[16 + cl][kb], fAl1 = *(s16x8*)&Al[16 + cl][kb];
        s16x8 fBh0 = *(s16x8*)&Bh[n0w + cl][kb],      fBl0 = *(s16x8*)&Bl[n0w + cl][kb];
        s16x8 fBh1 = *(s16x8*)&Bh[n0w + 16 + cl][kb], fBl1 = *(s16x8*)&Bl[n0w + 16 + cl][kb];
        acc[0][0] = mfma16(fAh0, fBh0, acc[0][0]);
        acc[0][0] = mfma16(fAl0, fBh0, acc[0][0]);
        acc[0][0] = mfma16(fAh0, fBl0, acc[0][0]);
        acc[0][1] = mfma16(fAh0, fBh1, acc[0][1]);
        acc[0][1] = mfma16(fAl0, fBh1, acc[0][1]);
        acc[0][1] = mfma16(fAh0, fBl1, acc[0][1]);
        acc[1][0] = mfma16(fAh1, fBh0, acc[1][0]);
        acc[1][0] = mfma16(fAl1, fBh0, acc[1][0]);
        acc[1][0] = mfma16(fAh1, fBl0, acc[1][0]);
        acc[1][1] = mfma16(fAh1, fBh1, acc[1][1]);
        acc[1][1] = mfma16(fAl1, fBh1, acc[1][1]);
        acc[1][1] = mfma16(fAh1, fBl1, acc[1][1]);
    }

    __syncthreads();
    float* red = (float*)&Bh[0][0];   // scratch: Bh alone is 9216 B >= 8192 B needed; all Bh reads done
    if (kh == 1) {
        float* rp = red + (w & 1) * 1024 + lane * 16;
#pragma unroll
        for (int mt = 0; mt < 2; ++mt)
#pragma unroll
            for (int nt = 0; nt < 2; ++nt)
#pragma unroll
                for (int r = 0; r < 4; ++r) rp[(mt * 2 + nt) * 4 + r] = acc[mt][nt][r];
    }
    __syncthreads();
    if (kh == 0) {
        const float* rp = red + (w & 1) * 1024 + lane * 16;
#pragma unroll
        for (int mt = 0; mt < 2; ++mt)
#pragma unroll
            for (int nt = 0; nt < 2; ++nt) {
                int col = c0 + n0w + nt * 16 + cl;
                float bb = bias ? bias[col] : 0.f;
#pragma unroll
                for (int r = 0; r < 4; ++r) {
                    float v = acc[mt][nt][r] + rp[(mt * 2 + nt) * 4 + r] + bb;
                    if (relu) v = fmaxf(v, 0.f);
                    C[(size_t)(r0 + mt * 16 + g * 4 + r) * NC + col] = v;
                }
            }
    }
}

// ---------------- flash attention v3: MFMA QK^T and PV, hi/lo split ----------------
// Block = (head, 32 q-rows), 4 waves. Per 64-key tile: wave w computes 32q x 16keys scores
// (2 MFMA m-tiles), cross-wave softmax state (m,l,sc per q-row) in LDS, then wave w computes
// PV output tile (mt=w>>1, nt=w&1) of the 32q x 32dh output, K=64 keys per tile.
// All-masked-prefix note: masked p=exp(0)=1 garbage accumulates while mrow==-1e30, but the
// first real (unmasked) key sets srow=exp(-1e30-s*)=0 which wipes lrow and accO; every row
// has >=1 unmasked key (mask diagonal is 0), so the final output is exact.

__global__ __launch_bounds__(256) void k_attn(const float* __restrict__ qkv, const unsigned* __restrict__ mbits,
                                              float* __restrict__ o) {
    __shared__ short Qh[32][40],  Ql[32][40];     // [q][dh]
    __shared__ short Kh[64][40],  Kl[64][40];     // [key][dh]
    __shared__ short Vth[32][72], Vtl[32][72];    // [dh][key]  (V^T)
    __shared__ short Ph[32][72],  Pl[32][72];     // [q][key]
    __shared__ float mrow[32], lrow[32], srow[32];
    __shared__ float pmax[4][32], psum[4][32];
    __shared__ unsigned mwv[32][2];

    int h = blockIdx.x, q0 = blockIdx.y * 32;
    int tid = threadIdx.x;
    int w = tid >> 6, lane = tid & 63;
    int g = lane >> 4, cl = lane & 15;
    const float scale = 0.17677669529663687f;   // 1/sqrt(32)

    {   // stage Q once (from fused qkv, row stride 768, col offset h*32)
        int row = tid >> 3, dq = (tid & 7) * 4;
        float4 qv = *(const float4*)(qkv + (size_t)(q0 + row) * 768 + h * DH_ + dq);
        float qa[4] = {qv.x, qv.y, qv.z, qv.w};
#pragma unroll
        for (int i = 0; i < 4; ++i) { short hh, ll; splitf(qa[i], hh, ll); Qh[row][dq + i] = hh; Ql[row][dq + i] = ll; }
    }
    if (tid < 32) { mrow[tid] = -3.0e38f; lrow[tid] = 0.f; }

    int mt = w >> 1, nt = w & 1;
    f32x4 accO = (f32x4){0.f, 0.f, 0.f, 0.f};

    for (int c0 = 0; c0 < S_; c0 += 64) {
        __syncthreads();                                   // b1
        {   // stage K (hi/lo, [key][dh]) and V^T (hi/lo, [dh][key])
            int key = tid & 63, d0 = (tid >> 6) * 8;
            const float* kp = qkv + (size_t)(c0 + key) * 768 + 256 + h * DH_ + d0;
            float4 k0v = *(const float4*)kp, k1v = *(const float4*)(kp + 4);
            float kv[8] = {k0v.x, k0v.y, k0v.z, k0v.w, k1v.x, k1v.y, k1v.z, k1v.w};
            s16x8 vh, vl;
#pragma unroll
            for (int i = 0; i < 8; ++i) { short hh, ll; splitf(kv[i], hh, ll); vh[i] = hh; vl[i] = ll; }
            *(s16x8*)&Kh[key][d0] = vh;
            *(s16x8*)&Kl[key][d0] = vl;
            const float* vp = qkv + (size_t)(c0 + key) * 768 + 512 + h * DH_ + d0;
            float4 v0v = *(const float4*)vp, v1v = *(const float4*)(vp + 4);
            float vv[8] = {v0v.x, v0v.y, v0v.z, v0v.w, v1v.x, v1v.y, v1v.z, v1v.w};
#pragma unroll
            for (int i = 0; i < 8; ++i) { short hh, ll; splitf(vv[i], hh, ll); Vth[d0 + i][key] = hh; Vtl[d0 + i][key] = ll; }
        }
        if (tid < 64) mwv[tid >> 1][tid & 1] = mbits[(size_t)(q0 + (tid >> 1)) * SW_ + (c0 >> 5) + (tid & 1)];
        __syncthreads();                                   // b2

        // ---- QK^T: wave w covers keys [w*16, w*16+16) ----
        int kfo = g * 8;
        s16x8 fQh0 = *(s16x8*)&Qh[cl][kfo],      fQl0 = *(s16x8*)&Ql[cl][kfo];
        s16x8 fQh1 = *(s16x8*)&Qh[16 + cl][kfo], fQl1 = *(s16x8*)&Ql[16 + cl][kfo];
        s16x8 fKh  = *(s16x8*)&Kh[w * 16 + cl][kfo], fKl = *(s16x8*)&Kl[w * 16 + cl][kfo];
        f32x4 s0 = (f32x4){0.f, 0.f, 0.f, 0.f}, s1 = (f32x4){0.f, 0.f, 0.f, 0.f};
        s0 = mfma16(fQh0, fKh, s0); s0 = mfma16(fQl0, fKh, s0); s0 = mfma16(fQh0, fKl, s0);
        s1 = mfma16(fQh1, fKh, s1); s1 = mfma16(fQl1, fKh, s1); s1 = mfma16(fQh1, fKl, s1);

        int keyl = w * 16 + cl;
        unsigned bitm = 1u << (keyl & 31);
        int widx = keyl >> 5;
        float sv[2][4];
#pragma unroll
        for (int r = 0; r < 4; ++r) {
            sv[0][r] = (mwv[g * 4 + r][widx]      & bitm) ? -1.0e30f : s0[r] * scale;
            sv[1][r] = (mwv[16 + g * 4 + r][widx] & bitm) ? -1.0e30f : s1[r] * scale;
        }
        float mx[2][4];
#pragma unroll
        for (int m2 = 0; m2 < 2; ++m2)
#pragma unroll
            for (int r = 0; r < 4; ++r) {
                float v = sv[m2][r];
                v = fmaxf(v, __shfl_xor(v, 1));
                v = fmaxf(v, __shfl_xor(v, 2));
                v = fmaxf(v, __shfl_xor(v, 4));
                v = fmaxf(v, __shfl_xor(v, 8));
                mx[m2][r] = v;
            }
        if (cl == 0) {
#pragma unroll
            for (int r = 0; r < 4; ++r) {
                pmax[w][g * 4 + r]      = mx[0][r];
                pmax[w][16 + g * 4 + r] = mx[1][r];
            }
        }
        __syncthreads();                                   // b3
        if (tid < 32) {
            float tm = fmaxf(fmaxf(pmax[0][tid], pmax[1][tid]), fmaxf(pmax[2][tid], pmax[3][tid]));
            float mo = mrow[tid];
            float mn = fmaxf(mo, tm);
            srow[tid] = __expf(mo - mn);    // mo = -3e38 first tile -> exp -> 0 (finite, no NaN)
            mrow[tid] = mn;
        }
        __syncthreads();                                   // b4
        float ps[2][4];
#pragma unroll
        for (int m2 = 0; m2 < 2; ++m2)
#pragma unroll
            for (int r = 0; r < 4; ++r) {
                int row = m2 * 16 + g * 4 + r;
                float p = __expf(sv[m2][r] - mrow[row]);   // masked: exp(-1e30 - m) = 0
                short ph = f2bf(p);
                Ph[row][keyl] = ph;
                Pl[row][keyl] = f2bf(p - bf2f(ph));
                ps[m2][r] = p;
            }
#pragma unroll
        for (int m2 = 0; m2 < 2; ++m2)
#pragma unroll
            for (int r = 0; r < 4; ++r) {
                float v = ps[m2][r];
                v += __shfl_xor(v, 1);
                v += __shfl_xor(v, 2);
                v += __shfl_xor(v, 4);
                v += __shfl_xor(v, 8);
                ps[m2][r] = v;
            }
        if (cl == 0) {
#pragma unroll
            for (int r = 0; r < 4; ++r) {
                psum[w][g * 4 + r]      = ps[0][r];
                psum[w][16 + g * 4 + r] = ps[1][r];
            }
        }
        __syncthreads();                                   // b5
        if (tid < 32)
            lrow[tid] = lrow[tid] * srow[tid] + psum[0][tid] + psum[1][tid] + psum[2][tid] + psum[3][tid];

        // ---- PV: wave computes its (mt, nt) 16x16 output tile over K=64 keys ----
#pragma unroll
        for (int r = 0; r < 4; ++r) accO[r] *= srow[mt * 16 + g * 4 + r];
#pragma unroll
        for (int kc = 0; kc < 2; ++kc) {
            int ko = kc * 32 + g * 8;
            s16x8 fPh = *(s16x8*)&Ph[mt * 16 + cl][ko], fPl = *(s16x8*)&Pl[mt * 16 + cl][ko];
            s16x8 fVh = *(s16x8*)&Vth[nt * 16 + cl][ko], fVl = *(s16x8*)&Vtl[nt * 16 + cl][ko];
            accO = mfma16(fPh, fVh, accO);
            accO = mfma16(fPl, fVh, accO);
            accO = mfma16(fPh, fVl, accO);
        }
    }
    __syncthreads();
#pragma unroll
    for (int r = 0; r < 4; ++r) {
        int row = mt * 16 + g * 4 + r;
        o[(size_t)(q0 + row) * D_ + h * DH_ + nt * 16 + cl] = accO[r] / lrow[row];
    }
}

// ---------------- residual add + LayerNorm ----------------

__global__ __launch_bounds__(256) void k_addln(float* __restrict__ x, const float* __restrict__ add,
                                               const float* __restrict__ gg, const float* __restrict__ bb) {
    int row = blockIdx.x, d = threadIdx.x;
    float val = x[row * D_ + d] + add[row * D_ + d];

    __shared__ float w4[4];
    __shared__ float bc[2];

    float ss = val;
    for (int o = 32; o; o >>= 1) ss += __shfl_down(ss, o, 64);
    if ((d & 63) == 0) w4[d >> 6] = ss;
    __syncthreads();
    if (d == 0) bc[0] = (w4[0] + w4[1] + w4[2] + w4[3]) * (1.f / D_);
    __syncthreads();
    float mu = bc[0];
    float c = val - mu;
    float vs = c * c;
    for (int o = 32; o; o >>= 1) vs += __shfl_down(vs, o, 64);
    __syncthreads();
    if ((d & 63) == 0) w4[d >> 6] = vs;
    __syncthreads();
    if (d == 0) bc[1] = (w4[0] + w4[1] + w4[2] + w4[3]) * (1.f / D_);
    __syncthreads();
    float var = bc[1];
    float rr = rsqrtf(var + 1e-6f);
    x[row * D_ + d] = c * rr * gg[d] + bb[d];
}

// ---------------- final projection ----------------

__global__ __launch_bounds__(256) void k_final(const float* __restrict__ x, const float* __restrict__ fcw,
                                               const float* __restrict__ fcb, const float* __restrict__ tnw,
                                               const float* __restrict__ tnb, float* __restrict__ out) {
    int row = blockIdx.x, d = threadIdx.x;
    float p = x[row * D_ + d] * fcw[d];
    for (int o = 32; o; o >>= 1) p += __shfl_down(p, o, 64);
    __shared__ float w4[4];
    if ((d & 63) == 0) w4[d >> 6] = p;
    __syncthreads();
    if (d == 0) {
        float s = w4[0] + w4[1] + w4[2] + w4[3];
        out[row] = (s + fcb[0]) * tnw[0] + tnb[0];
    }
}

// ---------------- launch ----------------

extern "C" void kernel_launch(void* const* d_in, const int* in_sizes, int n_in,
                              void* d_out, int out_size, void* d_ws, size_t ws_size,
                              hipStream_t stream) {
    const float* r_t   = (const float*)d_in[0];
    const float* H     = (const float*)d_in[1];
    const float* mask  = (const float*)d_in[2];
    const float* src   = (const float*)d_in[3];
    const float* tt    = (const float*)d_in[4];
    const float* Wq    = (const float*)d_in[5];
    const float* Wk    = (const float*)d_in[6];
    const float* Wv    = (const float*)d_in[7];
    const float* Wo    = (const float*)d_in[8];
    const float* W1    = (const float*)d_in[9];
    const float* b1    = (const float*)d_in[10];
    const float* W2    = (const float*)d_in[11];
    const float* b2    = (const float*)d_in[12];
    const float* ln1g  = (const float*)d_in[13];
    const float* ln1b  = (const float*)d_in[14];
    const float* ln2g  = (const float*)d_in[15];
    const float* ln2b  = (const float*)d_in[16];
    const float* fcw   = (const float*)d_in[17];
    const float* fcb   = (const float*)d_in[18];
    const float* tnw   = (const float*)d_in[19];
    const float* tnb   = (const float*)d_in[20];
    const int*   tptr  = (const int*)d_in[21];
    float* out = (float*)d_out;

    float* ws    = (float*)d_ws;
    float* x     = ws;                       // S*D      = 589824
    float* qkv   = x    + S_ * D_;           // S*768    = 1769472
    float* ao    = qkv  + S_ * 768;          // S*D
    float* tmp   = ao   + S_ * D_;           // S*D
    float* h1    = tmp  + S_ * D_;           // S*4D     = 2359296
    float* nodes = h1   + S_ * 4 * D_;       // S
    unsigned* mbits = (unsigned*)(nodes + S_);             // S*SW = 165888 words
    short* WqkvTh = (short*)(mbits + S_ * SW_);            // 6*768*256
    short* WqkvTl = WqkvTh + LAYERS_ * 768 * 256;
    short* WoTh   = WqkvTl + LAYERS_ * 768 * 256;          // 6*256*256
    short* WoTl   = WoTh   + LAYERS_ * 256 * 256;
    short* W1Th   = WoTl   + LAYERS_ * 256 * 256;          // 6*1024*256
    short* W1Tl   = W1Th   + LAYERS_ * 1024 * 256;
    short* W2Th   = W1Tl   + LAYERS_ * 1024 * 256;         // 6*256*1024
    short* W2Tl   = W2Th   + LAYERS_ * 256 * 1024;

    k_absr<<<(N_ + 255) / 256, 256, 0, stream>>>(r_t, nodes);
    k_synd<<<M_, 256, 0, stream>>>(r_t, H, nodes);
    k_maskpack<<<(S_ * SW_ + 255) / 256, 256, 0, stream>>>(mask, mbits);
    k_embed<<<S_, 256, 0, stream>>>(src, tt, tptr, nodes, x);

    // weight transpose+split: W[K][NC] -> WT[NC][K] hi/lo bf16
    k_wsplit<<<dim3(8, 8, 6),  256, 0, stream>>>(Wq, WqkvTh,             WqkvTl,             256, 256,  65536, 196608);
    k_wsplit<<<dim3(8, 8, 6),  256, 0, stream>>>(Wk, WqkvTh + 256 * 256, WqkvTl + 256 * 256, 256, 256,  65536, 196608);
    k_wsplit<<<dim3(8, 8, 6),  256, 0, stream>>>(Wv, WqkvTh + 512 * 256, WqkvTl + 512 * 256, 256, 256,  65536, 196608);
    k_wsplit<<<dim3(8, 8, 6),  256, 0, stream>>>(Wo, WoTh, WoTl, 256, 256,  65536, 65536);
    k_wsplit<<<dim3(32, 8, 6), 256, 0, stream>>>(W1, W1Th, W1Tl, 256, 1024, 262144, 262144);
    k_wsplit<<<dim3(8, 32, 6), 256, 0, stream>>>(W2, W2Th, W2Tl, 1024, 256, 262144, 262144);

    for (int i = 0; i < LAYERS_; ++i) {
        k_mgemm<<<dim3(12, 72), 256, 0, stream>>>(x, WqkvTh + (size_t)i * 196608, WqkvTl + (size_t)i * 196608,
                                                  qkv, 256, 768, nullptr, 0);
        k_attn<<<dim3(HEADS_, S_ / 32), 256, 0, stream>>>(qkv, mbits, ao);
        k_mgemm<<<dim3(4, 72), 256, 0, stream>>>(ao, WoTh + (size_t)i * 65536, WoTl + (size_t)i * 65536,
                                                 tmp, 256, 256, nullptr, 0);
        k_addln<<<S_, 256, 0, stream>>>(x, tmp, ln1g + i * D_, ln1b + i * D_);
        k_mgemm<<<dim3(16, 72), 256, 0, stream>>>(x, W1Th + (size_t)i * 262144, W1Tl + (size_t)i * 262144,
                                                  h1, 256, 1024, b1 + i * 4 * D_, 1);
        k_mgemm<<<dim3(4, 72), 256, 0, stream>>>(h1, W2Th + (size_t)i * 262144, W2Tl + (size_t)i * 262144,
                                                 tmp, 1024, 256, b2 + i * D_, 0);
        k_addln<<<S_, 256, 0, stream>>>(x, tmp, ln2g + i * D_, ln2b + i * D_);
    }

    k_final<<<N_, 256, 0, stream>>>(x, fcw, fcb, tnw, tnb, out);
}

// Round 7
// 1067.950 us; speedup vs baseline: 4.5138x; 1.3992x over previous
//
#include <hip/hip_runtime.h>
#include <math.h>

#define N_  1536
#define M_  768
#define D_  256
#define HEADS_ 8
#define DH_ 32
#define LAYERS_ 6
#define S_  2304
#define SW_ (S_/32)   // 72 mask words per row

typedef __attribute__((ext_vector_type(8))) short  s16x8;
typedef __attribute__((ext_vector_type(8))) __bf16 bf16x8;
typedef __attribute__((ext_vector_type(4))) float  f32x4;

static __device__ __forceinline__ f32x4 mfma16(s16x8 a, s16x8 b, f32x4 c) {
    return __builtin_amdgcn_mfma_f32_16x16x32_bf16(
        __builtin_bit_cast(bf16x8, a), __builtin_bit_cast(bf16x8, b), c, 0, 0, 0);
}

static __device__ __forceinline__ short f2bf(float f) {
    unsigned u = __builtin_bit_cast(unsigned, f);
    unsigned r = u + 0x7FFFu + ((u >> 16) & 1u);   // RNE to bf16
    return (short)(r >> 16);
}
static __device__ __forceinline__ float bf2f(short s) {
    unsigned u = ((unsigned)(unsigned short)s) << 16;
    return __builtin_bit_cast(float, u);
}
static __device__ __forceinline__ void splitf(float f, short& h, short& l) {
    h = f2bf(f);
    l = f2bf(f - bf2f(h));
}

// ---------------- prep kernels ----------------

__global__ __launch_bounds__(256) void k_absr(const float* __restrict__ r, float* __restrict__ nodes) {
    int i = blockIdx.x * 256 + threadIdx.x;
    if (i < N_) nodes[i] = fabsf(r[i]);
}

__global__ __launch_bounds__(256) void k_synd(const float* __restrict__ r, const float* __restrict__ H,
                                              float* __restrict__ nodes) {
    int row = blockIdx.x;
    int tid = threadIdx.x;
    float s = 0.f;
    for (int j = tid; j < N_; j += 256) {
        float b = (r[j] < 0.f) ? 1.f : 0.f;
        s += H[row * N_ + j] * b;
    }
    for (int o = 32; o; o >>= 1) s += __shfl_down(s, o, 64);
    __shared__ float w4[4];
    if ((tid & 63) == 0) w4[tid >> 6] = s;
    __syncthreads();
    if (tid == 0) {
        float t = w4[0] + w4[1] + w4[2] + w4[3];
        nodes[N_ + row] = fmodf(t, 2.0f);
    }
}

__global__ __launch_bounds__(256) void k_maskpack(const float* __restrict__ mask, unsigned* __restrict__ bits) {
    int w = blockIdx.x * 256 + threadIdx.x;
    if (w >= S_ * SW_) return;
    int row = w / SW_, c0 = (w % SW_) * 32;
    unsigned b = 0;
    const float* mrow = mask + (size_t)row * S_ + c0;
    for (int j = 0; j < 32; ++j)
        if (mrow[j] != 0.f) b |= (1u << j);
    bits[w] = b;
}

__global__ __launch_bounds__(256) void k_embed(const float* __restrict__ src, const float* __restrict__ tt,
                                               const int* __restrict__ tptr, const float* __restrict__ nodes,
                                               float* __restrict__ x) {
    int s = blockIdx.x, d = threadIdx.x;
    int t = tptr[0];
    x[s * D_ + d] = src[s * D_ + d] * nodes[s] * tt[t * D_ + d];
}

// ---------------- weight transpose + bf16 hi/lo split ----------------

__global__ __launch_bounds__(256) void k_wsplit(const float* __restrict__ W, short* __restrict__ oh,
                                                short* __restrict__ ol, int K, int NC,
                                                long in_ls, long out_ls) {
    __shared__ float T[32][33];
    int z = blockIdx.z;
    const float* Wz = W + (size_t)z * in_ls;
    short* ohz = oh + (size_t)z * out_ls;
    short* olz = ol + (size_t)z * out_ls;
    int n0 = blockIdx.x * 32, k0 = blockIdx.y * 32;
    int t = threadIdx.x;
    int r = t >> 3, c4 = (t & 7) * 4;
    float4 v = *(const float4*)(Wz + (size_t)(k0 + r) * NC + n0 + c4);
    T[r][c4 + 0] = v.x; T[r][c4 + 1] = v.y; T[r][c4 + 2] = v.z; T[r][c4 + 3] = v.w;
    __syncthreads();
    int n = t >> 3, k4 = (t & 7) * 4;
#pragma unroll
    for (int i = 0; i < 4; ++i) {
        float f = T[k4 + i][n];
        short hh, ll; splitf(f, hh, ll);
        ohz[(size_t)(n0 + n) * K + k0 + k4 + i] = hh;
        olz[(size_t)(n0 + n) * K + k0 + k4 + i] = ll;
    }
}

// ---------------- QKV pre-split kernels (once per layer) ----------------
// Q,K cols 0..511 of qkv[S][768] -> qkh/qkl[S][512]
__global__ __launch_bounds__(256) void k_qksplit(const float* __restrict__ qkv, short* __restrict__ qkh,
                                                 short* __restrict__ qkl) {
    int u = (blockIdx.x * 256 + threadIdx.x) * 8;
    int s = u >> 9, c = u & 511;
    const float* p = qkv + (size_t)s * 768 + c;
    float4 a = *(const float4*)p, b = *(const float4*)(p + 4);
    float v[8] = {a.x, a.y, a.z, a.w, b.x, b.y, b.z, b.w};
    s16x8 vh, vl;
#pragma unroll
    for (int i = 0; i < 8; ++i) { short hh, ll; splitf(v[i], hh, ll); vh[i] = hh; vl[i] = ll; }
    *(s16x8*)(qkh + u) = vh;
    *(s16x8*)(qkl + u) = vl;
}

// V cols 512..767 -> transposed vth/vtl[h*32+dh][S]  (LDS 64x32 tile transpose)
__global__ __launch_bounds__(256) void k_vsplit(const float* __restrict__ qkv, short* __restrict__ vth,
                                                short* __restrict__ vtl) {
    __shared__ short Th[32][72], Tl[32][72];
    int s0 = blockIdx.x * 64, h = blockIdx.y;
    int t = threadIdx.x;
    {
        int row = t >> 2, c8 = (t & 3) * 8;
        const float* p = qkv + (size_t)(s0 + row) * 768 + 512 + h * DH_ + c8;
        float4 a = *(const float4*)p, b = *(const float4*)(p + 4);
        float v[8] = {a.x, a.y, a.z, a.w, b.x, b.y, b.z, b.w};
#pragma unroll
        for (int i = 0; i < 8; ++i) { short hh, ll; splitf(v[i], hh, ll); Th[c8 + i][row] = hh; Tl[c8 + i][row] = ll; }
    }
    __syncthreads();
    {
        int dh = t >> 3, seg = (t & 7) * 8;
        *(s16x8*)(vth + (size_t)(h * DH_ + dh) * S_ + s0 + seg) = *(s16x8*)&Th[dh][seg];
        *(s16x8*)(vtl + (size_t)(h * DH_ + dh) * S_ + s0 + seg) = *(s16x8*)&Tl[dh][seg];
    }
}

// ---------------- MFMA GEMM (unchanged) ----------------

__global__ __launch_bounds__(256) void k_mgemm(const float* __restrict__ A, const short* __restrict__ BTh,
                                               const short* __restrict__ BTl, float* __restrict__ C,
                                               int K, int NC, const float* __restrict__ bias, int relu) {
    __shared__ short Ah[32][72], Al[32][72];
    __shared__ short Bh[64][72], Bl[64][72];
    int tid = threadIdx.x;
    int w = tid >> 6, lane = tid & 63;
    int n0w = (w & 1) * 32, kh = w >> 1;
    int r0 = blockIdx.y * 32, c0 = blockIdx.x * 64;
    int g = lane >> 4, cl = lane & 15;

    f32x4 acc[2][2];
#pragma unroll
    for (int mt = 0; mt < 2; ++mt)
#pragma unroll
        for (int nt = 0; nt < 2; ++nt) acc[mt][nt] = (f32x4){0.f, 0.f, 0.f, 0.f};

    int arow = tid >> 3, akq = (tid & 7) * 8;
    int bn = tid >> 2, bkq = (tid & 3) * 16;

    for (int k0 = 0; k0 < K; k0 += 64) {
        __syncthreads();
        {
            const float* ap = A + (size_t)(r0 + arow) * K + k0 + akq;
            float4 a0 = *(const float4*)ap, a1 = *(const float4*)(ap + 4);
            float av[8] = {a0.x, a0.y, a0.z, a0.w, a1.x, a1.y, a1.z, a1.w};
            s16x8 vh, vl;
#pragma unroll
            for (int i = 0; i < 8; ++i) { short hh, ll; splitf(av[i], hh, ll); vh[i] = hh; vl[i] = ll; }
            *(s16x8*)&Ah[arow][akq] = vh;
            *(s16x8*)&Al[arow][akq] = vl;
        }
        {
            const short* bph = BTh + (size_t)(c0 + bn) * K + k0 + bkq;
            const short* bpl = BTl + (size_t)(c0 + bn) * K + k0 + bkq;
            *(s16x8*)&Bh[bn][bkq]     = *(const s16x8*)bph;
            *(s16x8*)&Bh[bn][bkq + 8] = *(const s16x8*)(bph + 8);
            *(s16x8*)&Bl[bn][bkq]     = *(const s16x8*)bpl;
            *(s16x8*)&Bl[bn][bkq + 8] = *(const s16x8*)(bpl + 8);
        }
        __syncthreads();
        int kb = kh * 32 + g * 8;
        s16x8 fAh0 = *(s16x8*)&Ah[cl][kb],      fAl0 = *(s16x8*)&Al[cl][kb];
        s16x8 fAh1 = *(s16x8*)&Ah[16 + cl][kb], fAl1 = *(s16x8*)&Al[16 + cl][kb];
        s16x8 fBh0 = *(s16x8*)&Bh[n0w + cl][kb],      fBl0 = *(s16x8*)&Bl[n0w + cl][kb];
        s16x8 fBh1 = *(s16x8*)&Bh[n0w + 16 + cl][kb], fBl1 = *(s16x8*)&Bl[n0w + 16 + cl][kb];
        acc[0][0] = mfma16(fAh0, fBh0, acc[0][0]);
        acc[0][0] = mfma16(fAl0, fBh0, acc[0][0]);
        acc[0][0] = mfma16(fAh0, fBl0, acc[0][0]);
        acc[0][1] = mfma16(fAh0, fBh1, acc[0][1]);
        acc[0][1] = mfma16(fAl0, fBh1, acc[0][1]);
        acc[0][1] = mfma16(fAh0, fBl1, acc[0][1]);
        acc[1][0] = mfma16(fAh1, fBh0, acc[1][0]);
        acc[1][0] = mfma16(fAl1, fBh0, acc[1][0]);
        acc[1][0] = mfma16(fAh1, fBl0, acc[1][0]);
        acc[1][1] = mfma16(fAh1, fBh1, acc[1][1]);
        acc[1][1] = mfma16(fAl1, fBh1, acc[1][1]);
        acc[1][1] = mfma16(fAh1, fBl1, acc[1][1]);
    }

    __syncthreads();
    float* red = (float*)&Bh[0][0];
    if (kh == 1) {
        float* rp = red + (w & 1) * 1024 + lane * 16;
#pragma unroll
        for (int mt = 0; mt < 2; ++mt)
#pragma unroll
            for (int nt = 0; nt < 2; ++nt)
#pragma unroll
                for (int r = 0; r < 4; ++r) rp[(mt * 2 + nt) * 4 + r] = acc[mt][nt][r];
    }
    __syncthreads();
    if (kh == 0) {
        const float* rp = red + (w & 1) * 1024 + lane * 16;
#pragma unroll
        for (int mt = 0; mt < 2; ++mt)
#pragma unroll
            for (int nt = 0; nt < 2; ++nt) {
                int col = c0 + n0w + nt * 16 + cl;
                float bb = bias ? bias[col] : 0.f;
#pragma unroll
                for (int r = 0; r < 4; ++r) {
                    float v = acc[mt][nt][r] + rp[(mt * 2 + nt) * 4 + r] + bb;
                    if (relu) v = fmaxf(v, 0.f);
                    C[(size_t)(r0 + mt * 16 + g * 4 + r) * NC + col] = v;
                }
            }
    }
}

// ---------------- flash attention v4: wave-local softmax, pre-split inputs ----------------
// Block = (head, 32 q-rows), 2 waves x 64. Wave w owns q-rows w*16..w*16+15 and computes them
// against all 64 keys of the tile: QK^T = 4 n-tiles x 3-product (12 MFMA), softmax reduced via
// __shfl_xor over the 16-lane cl group (keys) + regs (n-tiles) -- NO cross-wave state, and only
// 2 barriers per tile (staging). P routed through per-wave LDS region (same-wave write->read).
// All-masked-prefix: masked p=exp(0)=1 garbage accumulates while mrow==-1e30; first real key
// sets srw=exp(-1e30-s*)=0 wiping lrow/accO; every row has >=1 unmasked key (mask diag 0).

__global__ __launch_bounds__(128) void k_attn(const short* __restrict__ qkh, const short* __restrict__ qkl,
                                              const short* __restrict__ vth, const short* __restrict__ vtl,
                                              const unsigned* __restrict__ mbits, float* __restrict__ o) {
    __shared__ short Qh[32][40], Ql[32][40];      // [q][dh]
    __shared__ short Kh[64][40], Kl[64][40];      // [key][dh]
    __shared__ short Vh[32][72], Vl[32][72];      // [dh][key] (V^T)
    __shared__ short Ph[32][72], Pl[32][72];      // [q][key], per-wave 16-row regions
    __shared__ unsigned mwv[32][2];

    int h = blockIdx.x, q0 = blockIdx.y * 32;
    int tid = threadIdx.x;
    int w = tid >> 6, lane = tid & 63;
    int g = lane >> 4, cl = lane & 15;
    int wq = w * 16;
    const float scale = 0.17677669529663687f;   // 1/sqrt(32)

    {   // stage Q once: 32 rows x 32 dh hi/lo
        int row = tid >> 2, s4 = (tid & 3) * 8;
        *(s16x8*)&Qh[row][s4] = *(const s16x8*)(qkh + (size_t)(q0 + row) * 512 + h * DH_ + s4);
        *(s16x8*)&Ql[row][s4] = *(const s16x8*)(qkl + (size_t)(q0 + row) * 512 + h * DH_ + s4);
    }

    float mrow[4], lrow[4];
#pragma unroll
    for (int r = 0; r < 4; ++r) { mrow[r] = -3.0e38f; lrow[r] = 0.f; }
    f32x4 accO[2] = {(f32x4){0.f,0.f,0.f,0.f}, (f32x4){0.f,0.f,0.f,0.f}};

    for (int c0 = 0; c0 < S_; c0 += 64) {
        __syncthreads();
        {   // stage K: 64 rows x 32 dh hi/lo (pure copies)
            int row = tid & 63, b0 = (tid >> 6) * 16;
            const short* ph = qkh + (size_t)(c0 + row) * 512 + 256 + h * DH_ + b0;
            const short* pl = qkl + (size_t)(c0 + row) * 512 + 256 + h * DH_ + b0;
            *(s16x8*)&Kh[row][b0]     = *(const s16x8*)ph;
            *(s16x8*)&Kh[row][b0 + 8] = *(const s16x8*)(ph + 8);
            *(s16x8*)&Kl[row][b0]     = *(const s16x8*)pl;
            *(s16x8*)&Kl[row][b0 + 8] = *(const s16x8*)(pl + 8);
        }
        {   // stage V^T: 32 dh x 64 keys hi/lo
            int dh = tid >> 2, b0 = (tid & 3) * 16;
            const short* ph = vth + (size_t)(h * DH_ + dh) * S_ + c0 + b0;
            const short* pl = vtl + (size_t)(h * DH_ + dh) * S_ + c0 + b0;
            *(s16x8*)&Vh[dh][b0]     = *(const s16x8*)ph;
            *(s16x8*)&Vh[dh][b0 + 8] = *(const s16x8*)(ph + 8);
            *(s16x8*)&Vl[dh][b0]     = *(const s16x8*)pl;
            *(s16x8*)&Vl[dh][b0 + 8] = *(const s16x8*)(pl + 8);
        }
        if (tid < 64) mwv[tid >> 1][tid & 1] = mbits[(size_t)(q0 + (tid >> 1)) * SW_ + (c0 >> 5) + (tid & 1)];
        __syncthreads();

        // ---- QK^T: wave's 16 q-rows vs all 64 keys ----
        s16x8 fQh = *(s16x8*)&Qh[wq + cl][g * 8], fQl = *(s16x8*)&Ql[wq + cl][g * 8];
        f32x4 sc[4];
#pragma unroll
        for (int nt2 = 0; nt2 < 4; ++nt2) {
            s16x8 fKh = *(s16x8*)&Kh[nt2 * 16 + cl][g * 8], fKl = *(s16x8*)&Kl[nt2 * 16 + cl][g * 8];
            f32x4 z = (f32x4){0.f, 0.f, 0.f, 0.f};
            z = mfma16(fQh, fKh, z);
            z = mfma16(fQl, fKh, z);
            z = mfma16(fQh, fKl, z);
            sc[nt2] = z;
        }

        // mask + scale; C layout: row q = g*4+r, col key = nt2*16+cl
        float sv[4][4];
#pragma unroll
        for (int nt2 = 0; nt2 < 4; ++nt2) {
            int wi = nt2 >> 1;
            unsigned bit = 1u << (((nt2 & 1) << 4) + cl);
#pragma unroll
            for (int r = 0; r < 4; ++r)
                sv[nt2][r] = (mwv[wq + g * 4 + r][wi] & bit) ? -1.0e30f : sc[nt2][r] * scale;
        }

        // wave-local online softmax (reduce over nt2 regs + cl lanes)
        float srw[4];
#pragma unroll
        for (int r = 0; r < 4; ++r) {
            float v = fmaxf(fmaxf(sv[0][r], sv[1][r]), fmaxf(sv[2][r], sv[3][r]));
            v = fmaxf(v, __shfl_xor(v, 1));
            v = fmaxf(v, __shfl_xor(v, 2));
            v = fmaxf(v, __shfl_xor(v, 4));
            v = fmaxf(v, __shfl_xor(v, 8));
            float mn = fmaxf(mrow[r], v);
            srw[r] = __expf(mrow[r] - mn);
            mrow[r] = mn;
            float psum = 0.f;
#pragma unroll
            for (int nt2 = 0; nt2 < 4; ++nt2) {
                float p = __expf(sv[nt2][r] - mn);
                psum += p;
                short ph = f2bf(p);
                Ph[wq + g * 4 + r][nt2 * 16 + cl] = ph;
                Pl[wq + g * 4 + r][nt2 * 16 + cl] = f2bf(p - bf2f(ph));
            }
            psum += __shfl_xor(psum, 1);
            psum += __shfl_xor(psum, 2);
            psum += __shfl_xor(psum, 4);
            psum += __shfl_xor(psum, 8);
            lrow[r] = lrow[r] * srw[r] + psum;
        }

        // ---- PV: wave's 16 q-rows x 32 dh over 64 keys ----
#pragma unroll
        for (int nt = 0; nt < 2; ++nt)
#pragma unroll
            for (int r = 0; r < 4; ++r) accO[nt][r] *= srw[r];
#pragma unroll
        for (int kc = 0; kc < 2; ++kc) {
            s16x8 fPh = *(s16x8*)&Ph[wq + cl][kc * 32 + g * 8];
            s16x8 fPl = *(s16x8*)&Pl[wq + cl][kc * 32 + g * 8];
#pragma unroll
            for (int nt = 0; nt < 2; ++nt) {
                s16x8 fVh = *(s16x8*)&Vh[nt * 16 + cl][kc * 32 + g * 8];
                s16x8 fVl = *(s16x8*)&Vl[nt * 16 + cl][kc * 32 + g * 8];
                accO[nt] = mfma16(fPh, fVh, accO[nt]);
                accO[nt] = mfma16(fPl, fVh, accO[nt]);
                accO[nt] = mfma16(fPh, fVl, accO[nt]);
            }
        }
    }

#pragma unroll
    for (int nt = 0; nt < 2; ++nt)
#pragma unroll
        for (int r = 0; r < 4; ++r) {
            int row = q0 + wq + g * 4 + r;
            o[(size_t)row * D_ + h * DH_ + nt * 16 + cl] = accO[nt][r] / lrow[r];
        }
}

// ---------------- residual add + LayerNorm ----------------

__global__ __launch_bounds__(256) void k_addln(float* __restrict__ x, const float* __restrict__ add,
                                               const float* __restrict__ gg, const float* __restrict__ bb) {
    int row = blockIdx.x, d = threadIdx.x;
    float val = x[row * D_ + d] + add[row * D_ + d];

    __shared__ float w4[4];
    __shared__ float bc[2];

    float ss = val;
    for (int o = 32; o; o >>= 1) ss += __shfl_down(ss, o, 64);
    if ((d & 63) == 0) w4[d >> 6] = ss;
    __syncthreads();
    if (d == 0) bc[0] = (w4[0] + w4[1] + w4[2] + w4[3]) * (1.f / D_);
    __syncthreads();
    float mu = bc[0];
    float c = val - mu;
    float vs = c * c;
    for (int o = 32; o; o >>= 1) vs += __shfl_down(vs, o, 64);
    __syncthreads();
    if ((d & 63) == 0) w4[d >> 6] = vs;
    __syncthreads();
    if (d == 0) bc[1] = (w4[0] + w4[1] + w4[2] + w4[3]) * (1.f / D_);
    __syncthreads();
    float var = bc[1];
    float rr = rsqrtf(var + 1e-6f);
    x[row * D_ + d] = c * rr * gg[d] + bb[d];
}

// ---------------- final projection ----------------

__global__ __launch_bounds__(256) void k_final(const float* __restrict__ x, const float* __restrict__ fcw,
                                               const float* __restrict__ fcb, const float* __restrict__ tnw,
                                               const float* __restrict__ tnb, float* __restrict__ out) {
    int row = blockIdx.x, d = threadIdx.x;
    float p = x[row * D_ + d] * fcw[d];
    for (int o = 32; o; o >>= 1) p += __shfl_down(p, o, 64);
    __shared__ float w4[4];
    if ((d & 63) == 0) w4[d >> 6] = p;
    __syncthreads();
    if (d == 0) {
        float s = w4[0] + w4[1] + w4[2] + w4[3];
        out[row] = (s + fcb[0]) * tnw[0] + tnb[0];
    }
}

// ---------------- launch ----------------

extern "C" void kernel_launch(void* const* d_in, const int* in_sizes, int n_in,
                              void* d_out, int out_size, void* d_ws, size_t ws_size,
                              hipStream_t stream) {
    const float* r_t   = (const float*)d_in[0];
    const float* H     = (const float*)d_in[1];
    const float* mask  = (const float*)d_in[2];
    const float* src   = (const float*)d_in[3];
    const float* tt    = (const float*)d_in[4];
    const float* Wq    = (const float*)d_in[5];
    const float* Wk    = (const float*)d_in[6];
    const float* Wv    = (const float*)d_in[7];
    const float* Wo    = (const float*)d_in[8];
    const float* W1    = (const float*)d_in[9];
    const float* b1    = (const float*)d_in[10];
    const float* W2    = (const float*)d_in[11];
    const float* b2    = (const float*)d_in[12];
    const float* ln1g  = (const float*)d_in[13];
    const float* ln1b  = (const float*)d_in[14];
    const float* ln2g  = (const float*)d_in[15];
    const float* ln2b  = (const float*)d_in[16];
    const float* fcw   = (const float*)d_in[17];
    const float* fcb   = (const float*)d_in[18];
    const float* tnw   = (const float*)d_in[19];
    const float* tnb   = (const float*)d_in[20];
    const int*   tptr  = (const int*)d_in[21];
    float* out = (float*)d_out;

    float* ws    = (float*)d_ws;
    float* x     = ws;                       // S*D
    float* qkv   = x    + S_ * D_;           // S*768
    float* ao    = qkv  + S_ * 768;          // S*D
    float* tmp   = ao   + S_ * D_;           // S*D
    float* h1    = tmp  + S_ * D_;           // S*4D
    float* nodes = h1   + S_ * 4 * D_;       // S
    unsigned* mbits = (unsigned*)(nodes + S_);             // S*SW words
    short* WqkvTh = (short*)(mbits + S_ * SW_);
    short* WqkvTl = WqkvTh + LAYERS_ * 768 * 256;
    short* WoTh   = WqkvTl + LAYERS_ * 768 * 256;
    short* WoTl   = WoTh   + LAYERS_ * 256 * 256;
    short* W1Th   = WoTl   + LAYERS_ * 256 * 256;
    short* W1Tl   = W1Th   + LAYERS_ * 1024 * 256;
    short* W2Th   = W1Tl   + LAYERS_ * 1024 * 256;
    short* W2Tl   = W2Th   + LAYERS_ * 256 * 1024;
    short* qkh    = W2Tl   + LAYERS_ * 256 * 1024;         // S*512
    short* qkl    = qkh    + S_ * 512;                     // S*512
    short* vth    = qkl    + S_ * 512;                     // 256*S
    short* vtl    = vth    + 256 * S_;                     // 256*S

    k_absr<<<(N_ + 255) / 256, 256, 0, stream>>>(r_t, nodes);
    k_synd<<<M_, 256, 0, stream>>>(r_t, H, nodes);
    k_maskpack<<<(S_ * SW_ + 255) / 256, 256, 0, stream>>>(mask, mbits);
    k_embed<<<S_, 256, 0, stream>>>(src, tt, tptr, nodes, x);

    k_wsplit<<<dim3(8, 8, 6),  256, 0, stream>>>(Wq, WqkvTh,             WqkvTl,             256, 256,  65536, 196608);
    k_wsplit<<<dim3(8, 8, 6),  256, 0, stream>>>(Wk, WqkvTh + 256 * 256, WqkvTl + 256 * 256, 256, 256,  65536, 196608);
    k_wsplit<<<dim3(8, 8, 6),  256, 0, stream>>>(Wv, WqkvTh + 512 * 256, WqkvTl + 512 * 256, 256, 256,  65536, 196608);
    k_wsplit<<<dim3(8, 8, 6),  256, 0, stream>>>(Wo, WoTh, WoTl, 256, 256,  65536, 65536);
    k_wsplit<<<dim3(32, 8, 6), 256, 0, stream>>>(W1, W1Th, W1Tl, 256, 1024, 262144, 262144);
    k_wsplit<<<dim3(8, 32, 6), 256, 0, stream>>>(W2, W2Th, W2Tl, 1024, 256, 262144, 262144);

    for (int i = 0; i < LAYERS_; ++i) {
        k_mgemm<<<dim3(12, 72), 256, 0, stream>>>(x, WqkvTh + (size_t)i * 196608, WqkvTl + (size_t)i * 196608,
                                                  qkv, 256, 768, nullptr, 0);
        k_qksplit<<<576, 256, 0, stream>>>(qkv, qkh, qkl);
        k_vsplit<<<dim3(36, 8), 256, 0, stream>>>(qkv, vth, vtl);
        k_attn<<<dim3(HEADS_, S_ / 32), 128, 0, stream>>>(qkh, qkl, vth, vtl, mbits, ao);
        k_mgemm<<<dim3(4, 72), 256, 0, stream>>>(ao, WoTh + (size_t)i * 65536, WoTl + (size_t)i * 65536,
                                                 tmp, 256, 256, nullptr, 0);
        k_addln<<<S_, 256, 0, stream>>>(x, tmp, ln1g + i * D_, ln1b + i * D_);
        k_mgemm<<<dim3(16, 72), 256, 0, stream>>>(x, W1Th + (size_t)i * 262144, W1Tl + (size_t)i * 262144,
                                                  h1, 256, 1024, b1 + i * 4 * D_, 1);
        k_mgemm<<<dim3(4, 72), 256, 0, stream>>>(h1, W2Th + (size_t)i * 262144, W2Tl + (size_t)i * 262144,
                                                 tmp, 1024, 256, b2 + i * D_, 0);
        k_addln<<<S_, 256, 0, stream>>>(x, tmp, ln2g + i * D_, ln2b + i * D_);
    }

    k_final<<<N_, 256, 0, stream>>>(x, fcw, fcb, tnw, tnb, out);
}

// Round 8
// 913.475 us; speedup vs baseline: 5.2771x; 1.1691x over previous
//
#include <hip/hip_runtime.h>
#include <math.h>

#define N_  1536
#define M_  768
#define D_  256
#define HEADS_ 8
#define DH_ 32
#define LAYERS_ 6
#define S_  2304
#define SW_ (S_/32)   // 72 mask words per row
#define NSPLIT_ 4
#define SPLEN_ (S_/NSPLIT_)   // 576 keys per split, 9 tiles of 64

typedef __attribute__((ext_vector_type(8))) short  s16x8;
typedef __attribute__((ext_vector_type(8))) __bf16 bf16x8;
typedef __attribute__((ext_vector_type(4))) float  f32x4;

static __device__ __forceinline__ f32x4 mfma16(s16x8 a, s16x8 b, f32x4 c) {
    return __builtin_amdgcn_mfma_f32_16x16x32_bf16(
        __builtin_bit_cast(bf16x8, a), __builtin_bit_cast(bf16x8, b), c, 0, 0, 0);
}

static __device__ __forceinline__ short f2bf(float f) {
    unsigned u = __builtin_bit_cast(unsigned, f);
    unsigned r = u + 0x7FFFu + ((u >> 16) & 1u);   // RNE to bf16
    return (short)(r >> 16);
}
static __device__ __forceinline__ float bf2f(short s) {
    unsigned u = ((unsigned)(unsigned short)s) << 16;
    return __builtin_bit_cast(float, u);
}
static __device__ __forceinline__ void splitf(float f, short& h, short& l) {
    h = f2bf(f);
    l = f2bf(f - bf2f(h));
}

// ---------------- prep kernels ----------------

__global__ __launch_bounds__(256) void k_absr(const float* __restrict__ r, float* __restrict__ nodes) {
    int i = blockIdx.x * 256 + threadIdx.x;
    if (i < N_) nodes[i] = fabsf(r[i]);
}

__global__ __launch_bounds__(256) void k_synd(const float* __restrict__ r, const float* __restrict__ H,
                                              float* __restrict__ nodes) {
    int row = blockIdx.x;
    int tid = threadIdx.x;
    float s = 0.f;
    for (int j = tid; j < N_; j += 256) {
        float b = (r[j] < 0.f) ? 1.f : 0.f;
        s += H[row * N_ + j] * b;
    }
    for (int o = 32; o; o >>= 1) s += __shfl_down(s, o, 64);
    __shared__ float w4[4];
    if ((tid & 63) == 0) w4[tid >> 6] = s;
    __syncthreads();
    if (tid == 0) {
        float t = w4[0] + w4[1] + w4[2] + w4[3];
        nodes[N_ + row] = fmodf(t, 2.0f);
    }
}

__global__ __launch_bounds__(256) void k_maskpack(const float* __restrict__ mask, unsigned* __restrict__ bits) {
    int w = blockIdx.x * 256 + threadIdx.x;
    if (w >= S_ * SW_) return;
    int row = w / SW_, c0 = (w % SW_) * 32;
    unsigned b = 0;
    const float* mrow = mask + (size_t)row * S_ + c0;
    for (int j = 0; j < 32; ++j)
        if (mrow[j] != 0.f) b |= (1u << j);
    bits[w] = b;
}

__global__ __launch_bounds__(256) void k_embed(const float* __restrict__ src, const float* __restrict__ tt,
                                               const int* __restrict__ tptr, const float* __restrict__ nodes,
                                               float* __restrict__ x) {
    int s = blockIdx.x, d = threadIdx.x;
    int t = tptr[0];
    x[s * D_ + d] = src[s * D_ + d] * nodes[s] * tt[t * D_ + d];
}

// ---------------- weight transpose + bf16 hi/lo split ----------------

__global__ __launch_bounds__(256) void k_wsplit(const float* __restrict__ W, short* __restrict__ oh,
                                                short* __restrict__ ol, int K, int NC,
                                                long in_ls, long out_ls) {
    __shared__ float T[32][33];
    int z = blockIdx.z;
    const float* Wz = W + (size_t)z * in_ls;
    short* ohz = oh + (size_t)z * out_ls;
    short* olz = ol + (size_t)z * out_ls;
    int n0 = blockIdx.x * 32, k0 = blockIdx.y * 32;
    int t = threadIdx.x;
    int r = t >> 3, c4 = (t & 7) * 4;
    float4 v = *(const float4*)(Wz + (size_t)(k0 + r) * NC + n0 + c4);
    T[r][c4 + 0] = v.x; T[r][c4 + 1] = v.y; T[r][c4 + 2] = v.z; T[r][c4 + 3] = v.w;
    __syncthreads();
    int n = t >> 3, k4 = (t & 7) * 4;
#pragma unroll
    for (int i = 0; i < 4; ++i) {
        float f = T[k4 + i][n];
        short hh, ll; splitf(f, hh, ll);
        ohz[(size_t)(n0 + n) * K + k0 + k4 + i] = hh;
        olz[(size_t)(n0 + n) * K + k0 + k4 + i] = ll;
    }
}

// ---------------- QKV pre-split kernels (once per layer) ----------------

__global__ __launch_bounds__(256) void k_qksplit(const float* __restrict__ qkv, short* __restrict__ qkh,
                                                 short* __restrict__ qkl) {
    int u = (blockIdx.x * 256 + threadIdx.x) * 8;
    int s = u >> 9, c = u & 511;
    const float* p = qkv + (size_t)s * 768 + c;
    float4 a = *(const float4*)p, b = *(const float4*)(p + 4);
    float v[8] = {a.x, a.y, a.z, a.w, b.x, b.y, b.z, b.w};
    s16x8 vh, vl;
#pragma unroll
    for (int i = 0; i < 8; ++i) { short hh, ll; splitf(v[i], hh, ll); vh[i] = hh; vl[i] = ll; }
    *(s16x8*)(qkh + u) = vh;
    *(s16x8*)(qkl + u) = vl;
}

__global__ __launch_bounds__(256) void k_vsplit(const float* __restrict__ qkv, short* __restrict__ vth,
                                                short* __restrict__ vtl) {
    __shared__ short Th[32][72], Tl[32][72];
    int s0 = blockIdx.x * 64, h = blockIdx.y;
    int t = threadIdx.x;
    {
        int row = t >> 2, c8 = (t & 3) * 8;
        const float* p = qkv + (size_t)(s0 + row) * 768 + 512 + h * DH_ + c8;
        float4 a = *(const float4*)p, b = *(const float4*)(p + 4);
        float v[8] = {a.x, a.y, a.z, a.w, b.x, b.y, b.z, b.w};
#pragma unroll
        for (int i = 0; i < 8; ++i) { short hh, ll; splitf(v[i], hh, ll); Th[c8 + i][row] = hh; Tl[c8 + i][row] = ll; }
    }
    __syncthreads();
    {
        int dh = t >> 3, seg = (t & 7) * 8;
        *(s16x8*)(vth + (size_t)(h * DH_ + dh) * S_ + s0 + seg) = *(s16x8*)&Th[dh][seg];
        *(s16x8*)(vtl + (size_t)(h * DH_ + dh) * S_ + s0 + seg) = *(s16x8*)&Tl[dh][seg];
    }
}

// ---------------- MFMA GEMM (unchanged) ----------------

__global__ __launch_bounds__(256) void k_mgemm(const float* __restrict__ A, const short* __restrict__ BTh,
                                               const short* __restrict__ BTl, float* __restrict__ C,
                                               int K, int NC, const float* __restrict__ bias, int relu) {
    __shared__ short Ah[32][72], Al[32][72];
    __shared__ short Bh[64][72], Bl[64][72];
    int tid = threadIdx.x;
    int w = tid >> 6, lane = tid & 63;
    int n0w = (w & 1) * 32, kh = w >> 1;
    int r0 = blockIdx.y * 32, c0 = blockIdx.x * 64;
    int g = lane >> 4, cl = lane & 15;

    f32x4 acc[2][2];
#pragma unroll
    for (int mt = 0; mt < 2; ++mt)
#pragma unroll
        for (int nt = 0; nt < 2; ++nt) acc[mt][nt] = (f32x4){0.f, 0.f, 0.f, 0.f};

    int arow = tid >> 3, akq = (tid & 7) * 8;
    int bn = tid >> 2, bkq = (tid & 3) * 16;

    for (int k0 = 0; k0 < K; k0 += 64) {
        __syncthreads();
        {
            const float* ap = A + (size_t)(r0 + arow) * K + k0 + akq;
            float4 a0 = *(const float4*)ap, a1 = *(const float4*)(ap + 4);
            float av[8] = {a0.x, a0.y, a0.z, a0.w, a1.x, a1.y, a1.z, a1.w};
            s16x8 vh, vl;
#pragma unroll
            for (int i = 0; i < 8; ++i) { short hh, ll; splitf(av[i], hh, ll); vh[i] = hh; vl[i] = ll; }
            *(s16x8*)&Ah[arow][akq] = vh;
            *(s16x8*)&Al[arow][akq] = vl;
        }
        {
            const short* bph = BTh + (size_t)(c0 + bn) * K + k0 + bkq;
            const short* bpl = BTl + (size_t)(c0 + bn) * K + k0 + bkq;
            *(s16x8*)&Bh[bn][bkq]     = *(const s16x8*)bph;
            *(s16x8*)&Bh[bn][bkq + 8] = *(const s16x8*)(bph + 8);
            *(s16x8*)&Bl[bn][bkq]     = *(const s16x8*)bpl;
            *(s16x8*)&Bl[bn][bkq + 8] = *(const s16x8*)(bpl + 8);
        }
        __syncthreads();
        int kb = kh * 32 + g * 8;
        s16x8 fAh0 = *(s16x8*)&Ah[cl][kb],      fAl0 = *(s16x8*)&Al[cl][kb];
        s16x8 fAh1 = *(s16x8*)&Ah[16 + cl][kb], fAl1 = *(s16x8*)&Al[16 + cl][kb];
        s16x8 fBh0 = *(s16x8*)&Bh[n0w + cl][kb],      fBl0 = *(s16x8*)&Bl[n0w + cl][kb];
        s16x8 fBh1 = *(s16x8*)&Bh[n0w + 16 + cl][kb], fBl1 = *(s16x8*)&Bl[n0w + 16 + cl][kb];
        acc[0][0] = mfma16(fAh0, fBh0, acc[0][0]);
        acc[0][0] = mfma16(fAl0, fBh0, acc[0][0]);
        acc[0][0] = mfma16(fAh0, fBl0, acc[0][0]);
        acc[0][1] = mfma16(fAh0, fBh1, acc[0][1]);
        acc[0][1] = mfma16(fAl0, fBh1, acc[0][1]);
        acc[0][1] = mfma16(fAh0, fBl1, acc[0][1]);
        acc[1][0] = mfma16(fAh1, fBh0, acc[1][0]);
        acc[1][0] = mfma16(fAl1, fBh0, acc[1][0]);
        acc[1][0] = mfma16(fAh1, fBl0, acc[1][0]);
        acc[1][1] = mfma16(fAh1, fBh1, acc[1][1]);
        acc[1][1] = mfma16(fAl1, fBh1, acc[1][1]);
        acc[1][1] = mfma16(fAh1, fBl1, acc[1][1]);
    }

    __syncthreads();
    float* red = (float*)&Bh[0][0];
    if (kh == 1) {
        float* rp = red + (w & 1) * 1024 + lane * 16;
#pragma unroll
        for (int mt = 0; mt < 2; ++mt)
#pragma unroll
            for (int nt = 0; nt < 2; ++nt)
#pragma unroll
                for (int r = 0; r < 4; ++r) rp[(mt * 2 + nt) * 4 + r] = acc[mt][nt][r];
    }
    __syncthreads();
    if (kh == 0) {
        const float* rp = red + (w & 1) * 1024 + lane * 16;
#pragma unroll
        for (int mt = 0; mt < 2; ++mt)
#pragma unroll
            for (int nt = 0; nt < 2; ++nt) {
                int col = c0 + n0w + nt * 16 + cl;
                float bb = bias ? bias[col] : 0.f;
#pragma unroll
                for (int r = 0; r < 4; ++r) {
                    float v = acc[mt][nt][r] + rp[(mt * 2 + nt) * 4 + r] + bb;
                    if (relu) v = fmaxf(v, 0.f);
                    C[(size_t)(r0 + mt * 16 + g * 4 + r) * NC + col] = v;
                }
            }
    }
}

// ---------------- flash attention v5: key-split + reg-prefetch staging ----------------
// Grid (head, qblock of 32, split of SPLEN_ keys). Block = 2 waves; wave w owns q-rows
// w*16..w*16+15, computes vs all 64 keys of each tile; wave-local softmax (shfl over cl).
// Writes UNNORMALIZED partial accO + (m,l) per row; k_acomb merges the NSPLIT_ partials.
// Staging is double-buffered through registers: global loads for tile t+1 issue before
// computing tile t (T14 async-stage split).
// Masked-only splits: p=exp(0)=1 garbage accumulates with m=-1e30; combine weight
// exp(-1e30 - M) = 0 cancels it exactly. Every row attends itself, so M is always real.

__global__ __launch_bounds__(128) void k_attn(const short* __restrict__ qkh, const short* __restrict__ qkl,
                                              const short* __restrict__ vth, const short* __restrict__ vtl,
                                              const unsigned* __restrict__ mbits,
                                              float* __restrict__ po, float* __restrict__ pml) {
    __shared__ short Qh[32][40], Ql[32][40];      // [q][dh]
    __shared__ short Kh[64][40], Kl[64][40];      // [key][dh]
    __shared__ short Vh[32][72], Vl[32][72];      // [dh][key] (V^T)
    __shared__ short Ph[32][72], Pl[32][72];      // [q][key], per-wave 16-row regions
    __shared__ unsigned mwv[32][2];

    int h = blockIdx.x, q0 = blockIdx.y * 32, sp = blockIdx.z;
    int c_begin = sp * SPLEN_, c_end = c_begin + SPLEN_;
    int tid = threadIdx.x;
    int w = tid >> 6, lane = tid & 63;
    int g = lane >> 4, cl = lane & 15;
    int wq = w * 16;
    const float scale = 0.17677669529663687f;   // 1/sqrt(32)

    {   // stage Q once
        int row = tid >> 2, s4 = (tid & 3) * 8;
        *(s16x8*)&Qh[row][s4] = *(const s16x8*)(qkh + (size_t)(q0 + row) * 512 + h * DH_ + s4);
        *(s16x8*)&Ql[row][s4] = *(const s16x8*)(qkl + (size_t)(q0 + row) * 512 + h * DH_ + s4);
    }

    // staging addresses (fixed per thread)
    int krow = tid & 63, kb0 = (tid >> 6) * 16;
    int vdh = tid >> 2, vb0 = (tid & 3) * 16;

    s16x8 rKh0, rKh1, rKl0, rKl1, rVh0, rVh1, rVl0, rVl1;
    {   // preload tile 0
        const short* ph = qkh + (size_t)(c_begin + krow) * 512 + 256 + h * DH_ + kb0;
        const short* pl = qkl + (size_t)(c_begin + krow) * 512 + 256 + h * DH_ + kb0;
        rKh0 = *(const s16x8*)ph; rKh1 = *(const s16x8*)(ph + 8);
        rKl0 = *(const s16x8*)pl; rKl1 = *(const s16x8*)(pl + 8);
        const short* vh = vth + (size_t)(h * DH_ + vdh) * S_ + c_begin + vb0;
        const short* vl = vtl + (size_t)(h * DH_ + vdh) * S_ + c_begin + vb0;
        rVh0 = *(const s16x8*)vh; rVh1 = *(const s16x8*)(vh + 8);
        rVl0 = *(const s16x8*)vl; rVl1 = *(const s16x8*)(vl + 8);
    }

    float mrow[4], lrow[4];
#pragma unroll
    for (int r = 0; r < 4; ++r) { mrow[r] = -3.0e38f; lrow[r] = 0.f; }
    f32x4 accO[2] = {(f32x4){0.f,0.f,0.f,0.f}, (f32x4){0.f,0.f,0.f,0.f}};

    for (int c0 = c_begin; c0 < c_end; c0 += 64) {
        __syncthreads();   // prev compute done; LDS reusable
        {   // reg -> LDS
            *(s16x8*)&Kh[krow][kb0]     = rKh0;
            *(s16x8*)&Kh[krow][kb0 + 8] = rKh1;
            *(s16x8*)&Kl[krow][kb0]     = rKl0;
            *(s16x8*)&Kl[krow][kb0 + 8] = rKl1;
            *(s16x8*)&Vh[vdh][vb0]      = rVh0;
            *(s16x8*)&Vh[vdh][vb0 + 8]  = rVh1;
            *(s16x8*)&Vl[vdh][vb0]      = rVl0;
            *(s16x8*)&Vl[vdh][vb0 + 8]  = rVl1;
        }
        if (tid < 64) mwv[tid >> 1][tid & 1] = mbits[(size_t)(q0 + (tid >> 1)) * SW_ + (c0 >> 5) + (tid & 1)];
        if (c0 + 64 < c_end) {   // prefetch next tile (overlaps with compute below)
            const short* ph = qkh + (size_t)(c0 + 64 + krow) * 512 + 256 + h * DH_ + kb0;
            const short* pl = qkl + (size_t)(c0 + 64 + krow) * 512 + 256 + h * DH_ + kb0;
            rKh0 = *(const s16x8*)ph; rKh1 = *(const s16x8*)(ph + 8);
            rKl0 = *(const s16x8*)pl; rKl1 = *(const s16x8*)(pl + 8);
            const short* vh = vth + (size_t)(h * DH_ + vdh) * S_ + c0 + 64 + vb0;
            const short* vl = vtl + (size_t)(h * DH_ + vdh) * S_ + c0 + 64 + vb0;
            rVh0 = *(const s16x8*)vh; rVh1 = *(const s16x8*)(vh + 8);
            rVl0 = *(const s16x8*)vl; rVl1 = *(const s16x8*)(vl + 8);
        }
        __syncthreads();

        // ---- QK^T: wave's 16 q-rows vs all 64 keys ----
        s16x8 fQh = *(s16x8*)&Qh[wq + cl][g * 8], fQl = *(s16x8*)&Ql[wq + cl][g * 8];
        f32x4 sc[4];
#pragma unroll
        for (int nt2 = 0; nt2 < 4; ++nt2) {
            s16x8 fKh = *(s16x8*)&Kh[nt2 * 16 + cl][g * 8], fKl = *(s16x8*)&Kl[nt2 * 16 + cl][g * 8];
            f32x4 z = (f32x4){0.f, 0.f, 0.f, 0.f};
            z = mfma16(fQh, fKh, z);
            z = mfma16(fQl, fKh, z);
            z = mfma16(fQh, fKl, z);
            sc[nt2] = z;
        }

        float sv[4][4];
#pragma unroll
        for (int nt2 = 0; nt2 < 4; ++nt2) {
            int wi = nt2 >> 1;
            unsigned bit = 1u << (((nt2 & 1) << 4) + cl);
#pragma unroll
            for (int r = 0; r < 4; ++r)
                sv[nt2][r] = (mwv[wq + g * 4 + r][wi] & bit) ? -1.0e30f : sc[nt2][r] * scale;
        }

        float srw[4];
#pragma unroll
        for (int r = 0; r < 4; ++r) {
            float v = fmaxf(fmaxf(sv[0][r], sv[1][r]), fmaxf(sv[2][r], sv[3][r]));
            v = fmaxf(v, __shfl_xor(v, 1));
            v = fmaxf(v, __shfl_xor(v, 2));
            v = fmaxf(v, __shfl_xor(v, 4));
            v = fmaxf(v, __shfl_xor(v, 8));
            float mn = fmaxf(mrow[r], v);
            srw[r] = __expf(mrow[r] - mn);
            mrow[r] = mn;
            float psum = 0.f;
#pragma unroll
            for (int nt2 = 0; nt2 < 4; ++nt2) {
                float p = __expf(sv[nt2][r] - mn);
                psum += p;
                short ph = f2bf(p);
                Ph[wq + g * 4 + r][nt2 * 16 + cl] = ph;
                Pl[wq + g * 4 + r][nt2 * 16 + cl] = f2bf(p - bf2f(ph));
            }
            psum += __shfl_xor(psum, 1);
            psum += __shfl_xor(psum, 2);
            psum += __shfl_xor(psum, 4);
            psum += __shfl_xor(psum, 8);
            lrow[r] = lrow[r] * srw[r] + psum;
        }

        // ---- PV ----
#pragma unroll
        for (int nt = 0; nt < 2; ++nt)
#pragma unroll
            for (int r = 0; r < 4; ++r) accO[nt][r] *= srw[r];
#pragma unroll
        for (int kc = 0; kc < 2; ++kc) {
            s16x8 fPh = *(s16x8*)&Ph[wq + cl][kc * 32 + g * 8];
            s16x8 fPl = *(s16x8*)&Pl[wq + cl][kc * 32 + g * 8];
#pragma unroll
            for (int nt = 0; nt < 2; ++nt) {
                s16x8 fVh = *(s16x8*)&Vh[nt * 16 + cl][kc * 32 + g * 8];
                s16x8 fVl = *(s16x8*)&Vl[nt * 16 + cl][kc * 32 + g * 8];
                accO[nt] = mfma16(fPh, fVh, accO[nt]);
                accO[nt] = mfma16(fPl, fVh, accO[nt]);
                accO[nt] = mfma16(fPh, fVl, accO[nt]);
            }
        }
    }

    // write unnormalized partial + (m, l)
#pragma unroll
    for (int nt = 0; nt < 2; ++nt)
#pragma unroll
        for (int r = 0; r < 4; ++r) {
            int row = q0 + wq + g * 4 + r;
            po[((size_t)sp * S_ + row) * D_ + h * DH_ + nt * 16 + cl] = accO[nt][r];
        }
    if (cl == 0) {
#pragma unroll
        for (int r = 0; r < 4; ++r) {
            int row = q0 + wq + g * 4 + r;
            size_t base = (((size_t)sp * S_ + row) * HEADS_ + h) * 2;
            pml[base] = mrow[r];
            pml[base + 1] = lrow[r];
        }
    }
}

// ---------------- flash split combine ----------------

__global__ __launch_bounds__(256) void k_acomb(const float* __restrict__ po, const float* __restrict__ pml,
                                               float* __restrict__ o) {
    int row = blockIdx.x, d = threadIdx.x, h = d >> 5;
    float m[NSPLIT_], l[NSPLIT_];
#pragma unroll
    for (int sp = 0; sp < NSPLIT_; ++sp) {
        size_t base = (((size_t)sp * S_ + row) * HEADS_ + h) * 2;
        m[sp] = pml[base];
        l[sp] = pml[base + 1];
    }
    float M = fmaxf(fmaxf(m[0], m[1]), fmaxf(m[2], m[3]));
    float L = 0.f, acc = 0.f;
#pragma unroll
    for (int sp = 0; sp < NSPLIT_; ++sp) {
        float wgt = __expf(m[sp] - M);   // empty/masked-only split -> 0, cancels garbage exactly
        L += l[sp] * wgt;
        acc += po[((size_t)sp * S_ + row) * D_ + d] * wgt;
    }
    o[(size_t)row * D_ + d] = acc / L;
}

// ---------------- residual add + LayerNorm ----------------

__global__ __launch_bounds__(256) void k_addln(float* __restrict__ x, const float* __restrict__ add,
                                               const float* __restrict__ gg, const float* __restrict__ bb) {
    int row = blockIdx.x, d = threadIdx.x;
    float val = x[row * D_ + d] + add[row * D_ + d];

    __shared__ float w4[4];
    __shared__ float bc[2];

    float ss = val;
    for (int o = 32; o; o >>= 1) ss += __shfl_down(ss, o, 64);
    if ((d & 63) == 0) w4[d >> 6] = ss;
    __syncthreads();
    if (d == 0) bc[0] = (w4[0] + w4[1] + w4[2] + w4[3]) * (1.f / D_);
    __syncthreads();
    float mu = bc[0];
    float c = val - mu;
    float vs = c * c;
    for (int o = 32; o; o >>= 1) vs += __shfl_down(vs, o, 64);
    __syncthreads();
    if ((d & 63) == 0) w4[d >> 6] = vs;
    __syncthreads();
    if (d == 0) bc[1] = (w4[0] + w4[1] + w4[2] + w4[3]) * (1.f / D_);
    __syncthreads();
    float var = bc[1];
    float rr = rsqrtf(var + 1e-6f);
    x[row * D_ + d] = c * rr * gg[d] + bb[d];
}

// ---------------- final projection ----------------

__global__ __launch_bounds__(256) void k_final(const float* __restrict__ x, const float* __restrict__ fcw,
                                               const float* __restrict__ fcb, const float* __restrict__ tnw,
                                               const float* __restrict__ tnb, float* __restrict__ out) {
    int row = blockIdx.x, d = threadIdx.x;
    float p = x[row * D_ + d] * fcw[d];
    for (int o = 32; o; o >>= 1) p += __shfl_down(p, o, 64);
    __shared__ float w4[4];
    if ((d & 63) == 0) w4[d >> 6] = p;
    __syncthreads();
    if (d == 0) {
        float s = w4[0] + w4[1] + w4[2] + w4[3];
        out[row] = (s + fcb[0]) * tnw[0] + tnb[0];
    }
}

// ---------------- launch ----------------

extern "C" void kernel_launch(void* const* d_in, const int* in_sizes, int n_in,
                              void* d_out, int out_size, void* d_ws, size_t ws_size,
                              hipStream_t stream) {
    const float* r_t   = (const float*)d_in[0];
    const float* H     = (const float*)d_in[1];
    const float* mask  = (const float*)d_in[2];
    const float* src   = (const float*)d_in[3];
    const float* tt    = (const float*)d_in[4];
    const float* Wq    = (const float*)d_in[5];
    const float* Wk    = (const float*)d_in[6];
    const float* Wv    = (const float*)d_in[7];
    const float* Wo    = (const float*)d_in[8];
    const float* W1    = (const float*)d_in[9];
    const float* b1    = (const float*)d_in[10];
    const float* W2    = (const float*)d_in[11];
    const float* b2    = (const float*)d_in[12];
    const float* ln1g  = (const float*)d_in[13];
    const float* ln1b  = (const float*)d_in[14];
    const float* ln2g  = (const float*)d_in[15];
    const float* ln2b  = (const float*)d_in[16];
    const float* fcw   = (const float*)d_in[17];
    const float* fcb   = (const float*)d_in[18];
    const float* tnw   = (const float*)d_in[19];
    const float* tnb   = (const float*)d_in[20];
    const int*   tptr  = (const int*)d_in[21];
    float* out = (float*)d_out;

    float* ws    = (float*)d_ws;
    float* x     = ws;                       // S*D
    float* qkv   = x    + S_ * D_;           // S*768
    float* ao    = qkv  + S_ * 768;          // S*D
    float* tmp   = ao   + S_ * D_;           // S*D
    float* h1    = tmp  + S_ * D_;           // S*4D
    float* nodes = h1   + S_ * 4 * D_;       // S
    unsigned* mbits = (unsigned*)(nodes + S_);             // S*SW words
    short* WqkvTh = (short*)(mbits + S_ * SW_);
    short* WqkvTl = WqkvTh + LAYERS_ * 768 * 256;
    short* WoTh   = WqkvTl + LAYERS_ * 768 * 256;
    short* WoTl   = WoTh   + LAYERS_ * 256 * 256;
    short* W1Th   = WoTl   + LAYERS_ * 256 * 256;
    short* W1Tl   = W1Th   + LAYERS_ * 1024 * 256;
    short* W2Th   = W1Tl   + LAYERS_ * 1024 * 256;
    short* W2Tl   = W2Th   + LAYERS_ * 256 * 1024;
    short* qkh    = W2Tl   + LAYERS_ * 256 * 1024;         // S*512
    short* qkl    = qkh    + S_ * 512;                     // S*512
    short* vth    = qkl    + S_ * 512;                     // 256*S
    short* vtl    = vth    + 256 * S_;                     // 256*S
    float* po     = (float*)(vtl + 256 * S_);              // NSPLIT*S*D
    float* pml    = po + (size_t)NSPLIT_ * S_ * D_;        // NSPLIT*S*HEADS*2

    k_absr<<<(N_ + 255) / 256, 256, 0, stream>>>(r_t, nodes);
    k_synd<<<M_, 256, 0, stream>>>(r_t, H, nodes);
    k_maskpack<<<(S_ * SW_ + 255) / 256, 256, 0, stream>>>(mask, mbits);
    k_embed<<<S_, 256, 0, stream>>>(src, tt, tptr, nodes, x);

    k_wsplit<<<dim3(8, 8, 6),  256, 0, stream>>>(Wq, WqkvTh,             WqkvTl,             256, 256,  65536, 196608);
    k_wsplit<<<dim3(8, 8, 6),  256, 0, stream>>>(Wk, WqkvTh + 256 * 256, WqkvTl + 256 * 256, 256, 256,  65536, 196608);
    k_wsplit<<<dim3(8, 8, 6),  256, 0, stream>>>(Wv, WqkvTh + 512 * 256, WqkvTl + 512 * 256, 256, 256,  65536, 196608);
    k_wsplit<<<dim3(8, 8, 6),  256, 0, stream>>>(Wo, WoTh, WoTl, 256, 256,  65536, 65536);
    k_wsplit<<<dim3(32, 8, 6), 256, 0, stream>>>(W1, W1Th, W1Tl, 256, 1024, 262144, 262144);
    k_wsplit<<<dim3(8, 32, 6), 256, 0, stream>>>(W2, W2Th, W2Tl, 1024, 256, 262144, 262144);

    for (int i = 0; i < LAYERS_; ++i) {
        k_mgemm<<<dim3(12, 72), 256, 0, stream>>>(x, WqkvTh + (size_t)i * 196608, WqkvTl + (size_t)i * 196608,
                                                  qkv, 256, 768, nullptr, 0);
        k_qksplit<<<576, 256, 0, stream>>>(qkv, qkh, qkl);
        k_vsplit<<<dim3(36, 8), 256, 0, stream>>>(qkv, vth, vtl);
        k_attn<<<dim3(HEADS_, S_ / 32, NSPLIT_), 128, 0, stream>>>(qkh, qkl, vth, vtl, mbits, po, pml);
        k_acomb<<<S_, 256, 0, stream>>>(po, pml, ao);
        k_mgemm<<<dim3(4, 72), 256, 0, stream>>>(ao, WoTh + (size_t)i * 65536, WoTl + (size_t)i * 65536,
                                                 tmp, 256, 256, nullptr, 0);
        k_addln<<<S_, 256, 0, stream>>>(x, tmp, ln1g + i * D_, ln1b + i * D_);
        k_mgemm<<<dim3(16, 72), 256, 0, stream>>>(x, W1Th + (size_t)i * 262144, W1Tl + (size_t)i * 262144,
                                                  h1, 256, 1024, b1 + i * 4 * D_, 1);
        k_mgemm<<<dim3(4, 72), 256, 0, stream>>>(h1, W2Th + (size_t)i * 262144, W2Tl + (size_t)i * 262144,
                                                 tmp, 1024, 256, b2 + i * D_, 0);
        k_addln<<<S_, 256, 0, stream>>>(x, tmp, ln2g + i * D_, ln2b + i * D_);
    }

    k_final<<<N_, 256, 0, stream>>>(x, fcw, fcb, tnw, tnb, out);
}